// Round 12
// baseline (17103.001 us; speedup 1.0000x reference)
//
#include <hip/hip_runtime.h>
#include <hip/hip_fp16.h>
#include <math.h>

#define NCH   1024            // 2048 timesteps / CH=2
#define KMAX  1034            // last event: R4 chunk 1023 at k = 1023+10
#define HID   64
typedef unsigned int uint;
typedef __attribute__((ext_vector_type(2))) _Float16 h2t;

__device__ __forceinline__ float sigmoid_(float x){ return 1.0f/(1.0f+__expf(-x)); }
__device__ __forceinline__ float tanh_(float x){ float e=__expf(2.0f*x); return 1.0f-2.0f/(e+1.0f); }

__device__ __forceinline__ float fdot2_(uint w, uint h, float acc){
#if __has_builtin(__builtin_amdgcn_fdot2)
    return __builtin_amdgcn_fdot2(__builtin_bit_cast(h2t,w), __builtin_bit_cast(h2t,h), acc, false);
#else
    __half2 wv = *reinterpret_cast<const __half2*>(&w);
    __half2 hv = *reinterpret_cast<const __half2*>(&h);
    float2 wf = __half22float2(wv), hf = __half22float2(hv);
    return fmaf(wf.x, hf.x, fmaf(wf.y, hf.y, acc));
#endif
}
__device__ __forceinline__ uint packh(float a, float b){
    uint ha = (uint)__half_as_ushort(__float2half(a));   // RNE
    uint hb = (uint)__half_as_ushort(__float2half(b));
    return (hb<<16)|ha;
}
__device__ __forceinline__ uint4 pack8(const float* p){
    return make_uint4(packh(p[0],p[1]), packh(p[2],p[3]), packh(p[4],p[5]), packh(p[6],p[7]));
}

#define DOT4(A, W, H) do{ \
    A=fdot2_((W).x,(H).x,A); A=fdot2_((W).y,(H).y,A); \
    A=fdot2_((W).z,(H).z,A); A=fdot2_((W).w,(H).w,A); }while(0)

// ---- pre-pass: pack LDS-resident-in-r11 weights into d_ws as fp16 uint4 ----
// gWo : [5][8][64]  o-gate W_hh rows (row 192+lane of layer L)
// gWih: [10][8][64] W_ih groups (grp 0,1: layer2 rows 128+; 2-5: layer3; 6-9: layer4)
__global__ __launch_bounds__(256)
void pack_weights(const float* __restrict__ W_ih_rest,  // [4,256,64]
                  const float* __restrict__ W_hh,       // [5,256,64]
                  uint4* __restrict__ gWo,
                  uint4* __restrict__ gWih)
{
    const int idx = blockIdx.x * 256 + threadIdx.x;   // 0..7679
    if (idx >= 7680) return;
    if (idx < 2560){
        const int lane = idx & 63, d = (idx >> 6) & 7, L = idx >> 9;
        gWo[idx] = pack8(W_hh + (size_t)L*256*64 + (size_t)(192+lane)*64 + 8*d);
    } else {
        const int j = idx - 2560;                      // (grp*8+d)*64+lane
        const int lane = j & 63, d = (j >> 6) & 7, grp = j >> 9;
        int ly, row;
        if (grp < 2){ ly = 1; row = 128 + grp*64 + lane; }    // layer 2 rows 128..255
        else if (grp < 6){ ly = 2; row = (grp-2)*64 + lane; } // layer 3 all rows
        else { ly = 3; row = (grp-6)*64 + lane; }             // layer 4 all rows
        gWih[j] = pack8(W_ih_rest + ((size_t)ly*256 + row)*64 + 8*d);
    }
}

// All 5 LSTM layers, wavefront-pipelined, ONE kernel.
// grid = 256 blocks (1 sample), block = 256 threads (4 waves, 256-VGPR cap).
// Round-12: the per-CU LDS pipe was ~70% saturated (r11: ~430 b128 ops x ~10cyc
// vs 7.1K-cyc supercycle) while VMEM sat idle. All steady-state WEIGHT reads
// (o-gate W_hh + 10 W_ih groups) move to global memory (pre-packed fp16 in d_ws,
// L2-resident 120KB/CU working set). s_wo/s_wih deleted; LDS = 23.5KB static
// + 60KB dynamic pad (occupancy shaping: keep 1 block/CU). Math is bit-identical
// to r11 (same fp16 weights, same dot order) -> absmax must stay 1.2207e-4.
// Roles/schedule unchanged (r9/r11-verified):
//   w0: R L0+L1 + xg[L4] rows 0-127     w1: R L2+L3 + xg[L4] rows 128-255
//   w2: R L4 + stage x + xg[L0](regs) + xg[L2] rows 128-255
//   w3: xg[L1](regs) + xg[L2] rows 0-127(regs) + xg[L3]
// stage x(c)@k=c; G_l(c)@k=c+1+2l; R_l(c)@k=c+2+2l.
__global__ __attribute__((amdgpu_waves_per_eu(1,1))) __launch_bounds__(256)
void lstm_pipe4(const float* __restrict__ x,          // [256,2048,45]
                const float* __restrict__ W_ih0,      // [256,45]
                const float* __restrict__ W_ih_rest,  // [4,256,64]
                const float* __restrict__ W_hh,       // [5,256,64]
                const float* __restrict__ b_ih,       // [5,256]
                const float* __restrict__ b_hh,       // [5,256]
                const uint4* __restrict__ gWo,        // [5][8][64] packed fp16
                const uint4* __restrict__ gWih,       // [10][8][64] packed fp16
                float* __restrict__ h_last)           // [256,64] (d_ws)
{
    __shared__ float s_xg[2][5][2][256];        // 20480 B  xg double buffer (fp32)
    __shared__ uint  s_hh[4][2][2][32];         //  2048 B  h handoff (fp16)
    __shared__ uint  s_h16[5][32];              //   640 B  per-layer running h (fp16)
    __shared__ uint  s_x[2][2][24];             //   384 B  staged x chunk (fp16, 45+3 pad)
    // static 23552 B + 61440 dynamic pad = 84992 -> 1 block/CU

    const int tid  = threadIdx.x;
    const int wave = tid >> 6;
    const int lane = tid & 63;
    const int sm   = blockIdx.x;
    const float* x_s = x + (size_t)sm * 2048 * 45;
    float* hlast_g = h_last + (size_t)sm * HID;

    uint4 wU[48];          // per-wave weight register file (192 dwords), static-indexed
    float b0=0,b1=0,b2=0,b3=0,b4=0,b5=0,b6=0,b7=0,b8=0,b9=0;
    float cA=0.f, cB=0.f;  // cell states

    // ================= init: pack reg weights, biases =================
    if (wave == 0 || wave == 1){
#pragma unroll
        for (int li=0; li<2; ++li){
            const int L = wave*2 + li;
            const float* base = W_hh + (size_t)L*256*64;
#pragma unroll
            for (int d=0; d<8; ++d){
                wU[li*24 + 0*8 + d] = pack8(base + (size_t)(  0+lane)*64 + 8*d);  // i
                wU[li*24 + 1*8 + d] = pack8(base + (size_t)( 64+lane)*64 + 8*d);  // f
                wU[li*24 + 2*8 + d] = pack8(base + (size_t)(128+lane)*64 + 8*d);  // g
            }
            if (lane<32) s_h16[L][lane]=0u;
        }
        { int r0 = 4*256 + wave*128 + lane, r1 = r0 + 64;
          b0 = b_ih[r0]+b_hh[r0]; b1 = b_ih[r1]+b_hh[r1]; }
    } else if (wave == 2){
        const float* base = W_hh + (size_t)4*256*64;
#pragma unroll
        for (int d=0; d<8; ++d){
            wU[0*8+d] = pack8(base + (size_t)(  0+lane)*64 + 8*d);
            wU[1*8+d] = pack8(base + (size_t)( 64+lane)*64 + 8*d);
            wU[2*8+d] = pack8(base + (size_t)(128+lane)*64 + 8*d);
        }
        if (lane<32) s_h16[4][lane]=0u;
#pragma unroll
        for (int g=0; g<4; ++g){
            const float* src = W_ih0 + (size_t)(g*64+lane)*45;
#pragma unroll
            for (int d=0; d<6; ++d){
                float e0=(8*d+0<45)?src[8*d+0]:0.f, e1=(8*d+1<45)?src[8*d+1]:0.f;
                float e2=(8*d+2<45)?src[8*d+2]:0.f, e3=(8*d+3<45)?src[8*d+3]:0.f;
                float e4=(8*d+4<45)?src[8*d+4]:0.f, e5=(8*d+5<45)?src[8*d+5]:0.f;
                float e6=(8*d+6<45)?src[8*d+6]:0.f, e7=(8*d+7<45)?src[8*d+7]:0.f;
                wU[24 + g*6 + d] = make_uint4(packh(e0,e1),packh(e2,e3),packh(e4,e5),packh(e6,e7));
            }
        }
        { int r;
          r=      lane; b0=b_ih[r]+b_hh[r];
          r=  64+lane;  b1=b_ih[r]+b_hh[r];
          r= 128+lane;  b2=b_ih[r]+b_hh[r];
          r= 192+lane;  b3=b_ih[r]+b_hh[r]; }
        { int r0=2*256+128+lane, r1=2*256+192+lane;
          b4=b_ih[r0]+b_hh[r0]; b5=b_ih[r1]+b_hh[r1]; }
        if (lane < 12){
            int bb=lane/6, t=(lane%6)/3, d=45+lane%3;
            ((__half*)&s_x[bb][t][0])[d]=__float2half(0.f);
        }
    } else { // wave 3
#pragma unroll
        for (int g=0; g<6; ++g){
            const int ly  = (g<4) ? 1 : 2;
            const int row = (g<4) ? g*64+lane : (g-4)*64+lane;
            const float* src = W_ih_rest + ((size_t)(ly-1)*256 + row)*64;
#pragma unroll
            for (int d=0; d<8; ++d) wU[g*8+d] = pack8(src + 8*d);
        }
        { int r;
          r=1*256+  0+lane; b0=b_ih[r]+b_hh[r];
          r=1*256+ 64+lane; b1=b_ih[r]+b_hh[r];
          r=1*256+128+lane; b2=b_ih[r]+b_hh[r];
          r=1*256+192+lane; b3=b_ih[r]+b_hh[r];
          r=2*256+  0+lane; b4=b_ih[r]+b_hh[r];
          r=2*256+ 64+lane; b5=b_ih[r]+b_hh[r];
          r=3*256+  0+lane; b6=b_ih[r]+b_hh[r];
          r=3*256+ 64+lane; b7=b_ih[r]+b_hh[r];
          r=3*256+128+lane; b8=b_ih[r]+b_hh[r];
          r=3*256+192+lane; b9=b_ih[r]+b_hh[r]; }
    }
    __syncthreads();

// ---- recurrence step, no-lo, even/odd-d split chains; o-weights from GLOBAL ----
#define R_STEPN(L, WB, LASTF, T, C, CST) do{                                   \
    const int buf_ = (C)&1;                                                    \
    float xi_ = s_xg[buf_][L][T][      lane];                                  \
    float xf_ = s_xg[buf_][L][T][ 64 + lane];                                  \
    float xgg_= s_xg[buf_][L][T][128 + lane];                                  \
    float xo_ = s_xg[buf_][L][T][192 + lane];                                  \
    float ai0=0,ai1=0, af0=0,af1=0, ag0=0,ag1=0, ao0=0,ao1=0;                  \
    _Pragma("unroll")                                                          \
    for (int d_=0; d_<8; d_+=2){                                               \
        uint4 h0_ = *(const uint4*)&s_h16[L][4*d_];                            \
        uint4 h1_ = *(const uint4*)&s_h16[L][4*d_+4];                          \
        uint4 woA_ = gWo[((L)*8 + d_    )*64 + lane];                          \
        uint4 woB_ = gWo[((L)*8 + d_ + 1)*64 + lane];                          \
        DOT4(ai0, wU[(WB)+d_],      h0_); DOT4(ai1, wU[(WB)+d_+1],    h1_);    \
        DOT4(af0, wU[(WB)+8+d_],    h0_); DOT4(af1, wU[(WB)+8+d_+1],  h1_);    \
        DOT4(ag0, wU[(WB)+16+d_],   h0_); DOT4(ag1, wU[(WB)+16+d_+1], h1_);    \
        DOT4(ao0, woA_,             h0_); DOT4(ao1, woB_,             h1_);    \
    }                                                                          \
    float I_=sigmoid_(xi_+(ai0+ai1)), F_=sigmoid_(xf_+(af0+af1));              \
    float G_=tanh_(xgg_+(ag0+ag1)),   O_=sigmoid_(xo_+(ao0+ao1));              \
    CST = fmaf(F_, CST, I_*G_);                                                \
    float h_ = O_*tanh_(CST);                                                  \
    __half hhi_=__float2half(h_);                                              \
    ((__half*)&s_h16[L][0])[lane]=hhi_;                                        \
    if (!(LASTF)){                                                             \
        ((__half*)&s_hh[(L)<4?(L):0][buf_][T][0])[lane]=hhi_;                  \
    } else if ((C)==NCH-1 && (T)==1){ hlast_g[lane]=h_; }                      \
}while(0)

// ---- G blocks, no-lo, d-outer / t-inner ----
#define G4T(DMAX, WEXPR, H0, H1, XD0, XD1, B0_,B1_,B2_,B3_) do{                \
    float a00=(B0_),a01=(B1_),a02=(B2_),a03=(B3_);                             \
    float a10=(B0_),a11=(B1_),a12=(B2_),a13=(B3_);                             \
    _Pragma("unroll")                                                          \
    for (int d_=0; d_<(DMAX); ++d_){                                           \
        uint4 w0_=WEXPR(0,d_), w1_=WEXPR(1,d_), w2_=WEXPR(2,d_), w3_=WEXPR(3,d_);\
        uint4 h0_=*(const uint4*)&(H0)[4*d_];                                  \
        uint4 h1_=*(const uint4*)&(H1)[4*d_];                                  \
        DOT4(a00,w0_,h0_); DOT4(a01,w1_,h0_); DOT4(a02,w2_,h0_); DOT4(a03,w3_,h0_);\
        DOT4(a10,w0_,h1_); DOT4(a11,w1_,h1_); DOT4(a12,w2_,h1_); DOT4(a13,w3_,h1_);\
    }                                                                          \
    (XD0)[      lane]=a00; (XD0)[ 64+lane]=a01;                                \
    (XD0)[128+lane]=a02;   (XD0)[192+lane]=a03;                                \
    (XD1)[      lane]=a10; (XD1)[ 64+lane]=a11;                                \
    (XD1)[128+lane]=a12;   (XD1)[192+lane]=a13;                                \
}while(0)

#define G2T(DMAX, WEXPR, H0, H1, XD0, XD1, ROWOFF, B0_,B1_) do{                \
    float a00=(B0_),a01=(B1_), a10=(B0_),a11=(B1_);                            \
    _Pragma("unroll")                                                          \
    for (int d_=0; d_<(DMAX); ++d_){                                           \
        uint4 wa_ = WEXPR(0,d_), wb_ = WEXPR(1,d_);                            \
        uint4 h0_=*(const uint4*)&(H0)[4*d_];                                  \
        uint4 h1_=*(const uint4*)&(H1)[4*d_];                                  \
        DOT4(a00,wa_,h0_); DOT4(a01,wb_,h0_);                                  \
        DOT4(a10,wa_,h1_); DOT4(a11,wb_,h1_);                                  \
    }                                                                          \
    (XD0)[(ROWOFF)+lane]=a00; (XD0)[(ROWOFF)+64+lane]=a01;                     \
    (XD1)[(ROWOFF)+lane]=a10; (XD1)[(ROWOFF)+64+lane]=a11;                     \
}while(0)

// weight selectors: regs (wU) or GLOBAL (gWih, L2-resident)
#define W_L1(g,d)  wU[(g)*8+(d)]
#define W_L2R(g,d) wU[32+(g)*8+(d)]
#define W_L0(g,d)  wU[24+(g)*6+(d)]
#define W_L2L(g,d) (gWih[(((g)    )*8+(d))*64 + lane])
#define W_L3(g,d)  (gWih[((2+(g))*8+(d))*64 + lane])
#define W_L4A(g,d) (gWih[((6+(g))*8+(d))*64 + lane])
#define W_L4B(g,d) (gWih[((8+(g))*8+(d))*64 + lane])

#define STAGE_X() do{                                                          \
    const int bufx = k & 1;                                                    \
    _Pragma("unroll")                                                          \
    for (int r=0; r<2; ++r){                                                   \
        const int i = lane + 64*r;                                             \
        if (i < 90){                                                           \
            float v = x_s[(size_t)k*90 + i];                                   \
            const int t = i/45, d = i - 45*t;                                  \
            ((__half*)&s_x[bufx][t][0])[d] = __float2half(v);                  \
        }                                                                      \
    }                                                                          \
}while(0)

// per-wave supercycle bodies (shared by fast/slow path; guards only in slow)
#define BODY_W0(GUARDED) do{                                                   \
    const int c0=k-2, c1=k-4, cl=k-9;                                          \
    if (!(GUARDED) || (c0>=0 && c0<NCH)){ R_STEPN(0,  0, 0, 0, c0, cA); }      \
    if (!(GUARDED) || (c1>=0 && c1<NCH)){ R_STEPN(1, 24, 0, 0, c1, cB); }      \
    if (!(GUARDED) || (c0>=0 && c0<NCH)){ R_STEPN(0,  0, 0, 1, c0, cA); }      \
    if (!(GUARDED) || (c1>=0 && c1<NCH)){ R_STEPN(1, 24, 0, 1, c1, cB); }      \
    if (!(GUARDED) || (cl>=0 && cl<NCH)){                                      \
        const int bl=cl&1;                                                     \
        G2T(8, W_L4A, (&s_hh[3][bl][0][0]), (&s_hh[3][bl][1][0]),              \
            (&s_xg[bl][4][0][0]), (&s_xg[bl][4][1][0]), 0, b0,b1); }           \
}while(0)

#define BODY_W1(GUARDED) do{                                                   \
    const int c2=k-6, c3=k-8, cl=k-9;                                          \
    if (!(GUARDED) || (c2>=0 && c2<NCH)){ R_STEPN(2,  0, 0, 0, c2, cA); }      \
    if (!(GUARDED) || (c3>=0 && c3<NCH)){ R_STEPN(3, 24, 0, 0, c3, cB); }      \
    if (!(GUARDED) || (c2>=0 && c2<NCH)){ R_STEPN(2,  0, 0, 1, c2, cA); }      \
    if (!(GUARDED) || (c3>=0 && c3<NCH)){ R_STEPN(3, 24, 0, 1, c3, cB); }      \
    if (!(GUARDED) || (cl>=0 && cl<NCH)){                                      \
        const int bl=cl&1;                                                     \
        G2T(8, W_L4B, (&s_hh[3][bl][0][0]), (&s_hh[3][bl][1][0]),              \
            (&s_xg[bl][4][0][0]), (&s_xg[bl][4][1][0]), 128, b0,b1); }         \
}while(0)

#define BODY_W2(GUARDED) do{                                                   \
    if (!(GUARDED) || (k < NCH)) STAGE_X();                                    \
    const int c4=k-10, cg0=k-1, cg2=k-5;                                       \
    if (!(GUARDED) || (c4>=0 && c4<NCH)){ R_STEPN(4, 0, 1, 0, c4, cA); }       \
    if (!(GUARDED) || (cg0>=0 && cg0<NCH)){                                    \
        const int bg=cg0&1;                                                    \
        G4T(6, W_L0, (&s_x[bg][0][0]), (&s_x[bg][1][0]),                       \
            (&s_xg[bg][0][0][0]), (&s_xg[bg][0][1][0]), b0,b1,b2,b3); }        \
    if (!(GUARDED) || (c4>=0 && c4<NCH)){ R_STEPN(4, 0, 1, 1, c4, cA); }       \
    if (!(GUARDED) || (cg2>=0 && cg2<NCH)){                                    \
        const int bg=cg2&1;                                                    \
        G2T(8, W_L2L, (&s_hh[1][bg][0][0]), (&s_hh[1][bg][1][0]),              \
            (&s_xg[bg][2][0][0]), (&s_xg[bg][2][1][0]), 128, b4,b5); }         \
}while(0)

#define BODY_W3(GUARDED) do{                                                   \
    const int cg1=k-3, cg2=k-5, cg3=k-7;                                       \
    if (!(GUARDED) || (cg1>=0 && cg1<NCH)){                                    \
        const int bg=cg1&1;                                                    \
        G4T(8, W_L1, (&s_hh[0][bg][0][0]), (&s_hh[0][bg][1][0]),               \
            (&s_xg[bg][1][0][0]), (&s_xg[bg][1][1][0]), b0,b1,b2,b3); }        \
    if (!(GUARDED) || (cg2>=0 && cg2<NCH)){                                    \
        const int bg=cg2&1;                                                    \
        G2T(8, W_L2R, (&s_hh[1][bg][0][0]), (&s_hh[1][bg][1][0]),              \
            (&s_xg[bg][2][0][0]), (&s_xg[bg][2][1][0]), 0, b4,b5); }           \
    if (!(GUARDED) || (cg3>=0 && cg3<NCH)){                                    \
        const int bg=cg3&1;                                                    \
        G4T(8, W_L3, (&s_hh[2][bg][0][0]), (&s_hh[2][bg][1][0]),               \
            (&s_xg[bg][3][0][0]), (&s_xg[bg][3][1][0]), b6,b7,b8,b9); }        \
}while(0)

    // ================= supercycle loop =================
    for (int k=0; k<KMAX; ++k){
        if (k >= 10 && k < NCH){
            if      (wave == 0) BODY_W0(0);
            else if (wave == 1) BODY_W1(0);
            else if (wave == 2) BODY_W2(0);
            else                BODY_W3(0);
        } else {
            if      (wave == 0) BODY_W0(1);
            else if (wave == 1) BODY_W1(1);
            else if (wave == 2) BODY_W2(1);
            else                BODY_W3(1);
        }
        __syncthreads();
    }
}

// MLP head: features = gelu(last @ Wl^T + bl); out = relu(features @ Wo^T + bo)
// d_out layout: out[256*4] first, then features[256*128].
__global__ __launch_bounds__(128)
void head_kernel(const float* __restrict__ h_last,  // [256, 64]
                 const float* __restrict__ Wl,      // [128, 64]
                 const float* __restrict__ bl,      // [128]
                 const float* __restrict__ Wo,      // [4, 128]
                 const float* __restrict__ bo,      // [4]
                 float* __restrict__ d_out)
{
    __shared__ float s_last[HID];
    __shared__ float s_feat[128];
    const int s = blockIdx.x;
    const int j = threadIdx.x;

    if (j < HID) s_last[j] = h_last[(size_t)s * HID + j];
    __syncthreads();

    float acc = bl[j];
#pragma unroll
    for (int k = 0; k < HID; ++k)
        acc = fmaf(s_last[k], Wl[j * HID + k], acc);
    float f = 0.5f * acc * (1.0f + erff(acc * 0.70710678118654752440f));
    d_out[256 * 4 + s * 128 + j] = f;
    s_feat[j] = f;
    __syncthreads();

    if (j < 4) {
        float a = bo[j];
#pragma unroll
        for (int k = 0; k < 128; ++k)
            a = fmaf(s_feat[k], Wo[j * 128 + k], a);
        d_out[s * 4 + j] = fmaxf(a, 0.0f);
    }
}

extern "C" void kernel_launch(void* const* d_in, const int* in_sizes, int n_in,
                              void* d_out, int out_size, void* d_ws, size_t ws_size,
                              hipStream_t stream)
{
    const float* x         = (const float*)d_in[0];  // [256, 2048, 45]
    const float* W_ih0     = (const float*)d_in[1];  // [256, 45]
    const float* W_ih_rest = (const float*)d_in[2];  // [4, 256, 64]
    const float* W_hh      = (const float*)d_in[3];  // [5, 256, 64]
    const float* b_ih      = (const float*)d_in[4];  // [5, 256]
    const float* b_hh      = (const float*)d_in[5];  // [5, 256]
    const float* Wl        = (const float*)d_in[6];  // [128, 64]
    const float* bl        = (const float*)d_in[7];  // [128]
    const float* Wo        = (const float*)d_in[8];  // [4, 128]
    const float* bo        = (const float*)d_in[9];  // [4]

    // d_ws layout: [0,64K) h_last fp32; [64K,+40960) gWo; [+40960,+81920) gWih
    float* h_last = (float*)d_ws;
    uint4* gWo  = (uint4*)((char*)d_ws + 65536);
    uint4* gWih = (uint4*)((char*)d_ws + 65536 + 40960);

    pack_weights<<<30, 256, 0, stream>>>(W_ih_rest, W_hh, gWo, gWih);
    lstm_pipe4<<<256, 256, 61440, stream>>>(
        x, W_ih0, W_ih_rest, W_hh, b_ih, b_hh, gWo, gWih, h_last);
    head_kernel<<<256, 128, 0, stream>>>(h_last, Wl, bl, Wo, bo, (float*)d_out);
}

// Round 13
// 14455.380 us; speedup vs baseline: 1.1832x; 1.1832x over previous
//
#include <hip/hip_runtime.h>
#include <hip/hip_fp16.h>
#include <math.h>

#define CH    4
#define NCH   512             // 2048 timesteps / CH
#define KMAX  522             // last event: R4 chunk 511 at k = 511+10
#define HID   64
typedef unsigned int uint;
typedef __attribute__((ext_vector_type(2))) _Float16 h2t;

__device__ __forceinline__ float sigmoid_(float x){ return 1.0f/(1.0f+__expf(-x)); }
__device__ __forceinline__ float tanh_(float x){ float e=__expf(2.0f*x); return 1.0f-2.0f/(e+1.0f); }

__device__ __forceinline__ float fdot2_(uint w, uint h, float acc){
#if __has_builtin(__builtin_amdgcn_fdot2)
    return __builtin_amdgcn_fdot2(__builtin_bit_cast(h2t,w), __builtin_bit_cast(h2t,h), acc, false);
#else
    __half2 wv = *reinterpret_cast<const __half2*>(&w);
    __half2 hv = *reinterpret_cast<const __half2*>(&h);
    float2 wf = __half22float2(wv), hf = __half22float2(hv);
    return fmaf(wf.x, hf.x, fmaf(wf.y, hf.y, acc));
#endif
}
__device__ __forceinline__ uint packh(float a, float b){
    uint ha = (uint)__half_as_ushort(__float2half(a));   // RNE
    uint hb = (uint)__half_as_ushort(__float2half(b));
    return (hb<<16)|ha;
}
__device__ __forceinline__ uint4 pack8(const float* p){
    return make_uint4(packh(p[0],p[1]), packh(p[2],p[3]), packh(p[4],p[5]), packh(p[6],p[7]));
}

#define DOT4(A, W, H) do{ \
    A=fdot2_((W).x,(H).x,A); A=fdot2_((W).y,(H).y,A); \
    A=fdot2_((W).z,(H).z,A); A=fdot2_((W).w,(H).w,A); }while(0)

// All 5 LSTM layers, wavefront-pipelined, ONE kernel.
// grid = 256 blocks (1 sample), block = 256 threads (4 waves; VGPR cap law
// cap = 65536/block_threads -> 256; r9/r11 proved ~250 no-spill).
// Round-13: CH 2 -> 4 (522 supercycles instead of 1034). r11's supercycle was
// ~7.1K cyc with only ~2.5K of issue -> per-supercycle overheads (barrier,
// wave skew, LDS latency exposure at 1 wave/SIMD) dominate; halving their
// count + amortizing each G weight read over 4 timesteps attacks that
// directly. xg stored fp16 to fit LDS (error ~ same magnitude as existing
// fp16 weight rounding; r11 margin 4.6x). G tiles = 2 rows x 4 timesteps
// (~32 live regs, r10's spill trap avoided). Weights stay in VGPR/LDS
// (r12 proved global weights on the serial path are fatal).
// Roles (r9-verified schedule, offsets unchanged):
//   w0: R L0+L1 + xg[L4] rows 0-127     w1: R L2+L3 + xg[L4] rows 128-255
//   w2: R L4 + stage x + xg[L0](regs) + xg[L2] rows 128-255
//   w3: xg[L1](regs) + xg[L2] rows 0-127(regs) + xg[L3]
// stage x(c)@k=c; G_l(c)@k=c+1+2l; R_l(c)@k=c+2+2l.
__global__ __attribute__((amdgpu_waves_per_eu(1,1))) __launch_bounds__(256)
void lstm_pipe4(const float* __restrict__ x,          // [256,2048,45]
                const float* __restrict__ W_ih0,      // [256,45]
                const float* __restrict__ W_ih_rest,  // [4,256,64]
                const float* __restrict__ W_hh,       // [5,256,64]
                const float* __restrict__ b_ih,       // [5,256]
                const float* __restrict__ b_hh,       // [5,256]
                float* __restrict__ h_last)           // [256,64] (d_ws)
{
    __shared__ __half s_xg[2][5][CH][256];      // 20480 B  xg double buffer (fp16)
    __shared__ uint  s_wo [5][8][64][4];        // 40960 B  W_hh o-gate, fp16 packed
    __shared__ uint  s_wih[10][8][64][4];       // 81920 B  W_ih groups, fp16 packed
    __shared__ uint  s_hh[4][2][CH][32];        //  4096 B  h handoff (fp16)
    __shared__ uint  s_h16[5][32];              //   640 B  per-layer running h (fp16)
    __shared__ uint  s_x[2][CH][24];            //   768 B  staged x chunk (fp16, 45+3 pad)
    // total 148864 B -> 1 block/CU

    const int tid  = threadIdx.x;
    const int wave = tid >> 6;
    const int lane = tid & 63;
    const int sm   = blockIdx.x;
    const float* x_s = x + (size_t)sm * 2048 * 45;
    float* hlast_g = h_last + (size_t)sm * HID;

    uint4 wU[48];          // per-wave weight register file (192 dwords), static-indexed
    float b0=0,b1=0,b2=0,b3=0,b4=0,b5=0,b6=0,b7=0,b8=0,b9=0;
    float cA=0.f, cB=0.f;  // cell states

    // ================= init: pack weights, stage LDS (r9/r11-verified) =================
    if (wave == 0 || wave == 1){
#pragma unroll
        for (int li=0; li<2; ++li){
            const int L = wave*2 + li;
            const float* base = W_hh + (size_t)L*256*64;
#pragma unroll
            for (int d=0; d<8; ++d){
                wU[li*24 + 0*8 + d] = pack8(base + (size_t)(  0+lane)*64 + 8*d);  // i
                wU[li*24 + 1*8 + d] = pack8(base + (size_t)( 64+lane)*64 + 8*d);  // f
                wU[li*24 + 2*8 + d] = pack8(base + (size_t)(128+lane)*64 + 8*d);  // g
                *(uint4*)&s_wo[L][d][lane][0] = pack8(base + (size_t)(192+lane)*64 + 8*d); // o
            }
            if (lane<32) s_h16[L][lane]=0u;
        }
#pragma unroll
        for (int g=0; g<2; ++g){
            const int row = wave*128 + g*64 + lane;
            const float* src = W_ih_rest + ((size_t)3*256 + row)*64;
            const int grp = 6 + wave*2 + g;
#pragma unroll
            for (int d=0; d<8; ++d)
                *(uint4*)&s_wih[grp][d][lane][0] = pack8(src + 8*d);
        }
        { int r0 = 4*256 + wave*128 + lane, r1 = r0 + 64;
          b0 = b_ih[r0]+b_hh[r0]; b1 = b_ih[r1]+b_hh[r1]; }
    } else if (wave == 2){
        const float* base = W_hh + (size_t)4*256*64;
#pragma unroll
        for (int d=0; d<8; ++d){
            wU[0*8+d] = pack8(base + (size_t)(  0+lane)*64 + 8*d);
            wU[1*8+d] = pack8(base + (size_t)( 64+lane)*64 + 8*d);
            wU[2*8+d] = pack8(base + (size_t)(128+lane)*64 + 8*d);
            *(uint4*)&s_wo[4][d][lane][0] = pack8(base + (size_t)(192+lane)*64 + 8*d);
        }
        if (lane<32) s_h16[4][lane]=0u;
#pragma unroll
        for (int g=0; g<4; ++g){
            const float* src = W_ih0 + (size_t)(g*64+lane)*45;
#pragma unroll
            for (int d=0; d<6; ++d){
                float e0=(8*d+0<45)?src[8*d+0]:0.f, e1=(8*d+1<45)?src[8*d+1]:0.f;
                float e2=(8*d+2<45)?src[8*d+2]:0.f, e3=(8*d+3<45)?src[8*d+3]:0.f;
                float e4=(8*d+4<45)?src[8*d+4]:0.f, e5=(8*d+5<45)?src[8*d+5]:0.f;
                float e6=(8*d+6<45)?src[8*d+6]:0.f, e7=(8*d+7<45)?src[8*d+7]:0.f;
                wU[24 + g*6 + d] = make_uint4(packh(e0,e1),packh(e2,e3),packh(e4,e5),packh(e6,e7));
            }
        }
        { int r;
          r=      lane; b0=b_ih[r]+b_hh[r];
          r=  64+lane;  b1=b_ih[r]+b_hh[r];
          r= 128+lane;  b2=b_ih[r]+b_hh[r];
          r= 192+lane;  b3=b_ih[r]+b_hh[r]; }
#pragma unroll
        for (int g=0; g<2; ++g){
            const int row = 128 + g*64 + lane;
            const float* src = W_ih_rest + ((size_t)1*256 + row)*64;
#pragma unroll
            for (int d=0; d<8; ++d)
                *(uint4*)&s_wih[g][d][lane][0] = pack8(src + 8*d);
        }
        { int r0=2*256+128+lane, r1=2*256+192+lane;
          b4=b_ih[r0]+b_hh[r0]; b5=b_ih[r1]+b_hh[r1]; }
        // zero x pad halves (cols 45..47, all buf/t)
        if (lane < 2*CH*3){
            int bb=lane/(CH*3), rem=lane%(CH*3), t=rem/3, d=45+rem%3;
            ((__half*)&s_x[bb][t][0])[d]=__float2half(0.f);
        }
    } else { // wave 3
#pragma unroll
        for (int g=0; g<6; ++g){
            const int ly  = (g<4) ? 1 : 2;
            const int row = (g<4) ? g*64+lane : (g-4)*64+lane;
            const float* src = W_ih_rest + ((size_t)(ly-1)*256 + row)*64;
#pragma unroll
            for (int d=0; d<8; ++d) wU[g*8+d] = pack8(src + 8*d);
        }
        { int r;
          r=1*256+  0+lane; b0=b_ih[r]+b_hh[r];
          r=1*256+ 64+lane; b1=b_ih[r]+b_hh[r];
          r=1*256+128+lane; b2=b_ih[r]+b_hh[r];
          r=1*256+192+lane; b3=b_ih[r]+b_hh[r];
          r=2*256+  0+lane; b4=b_ih[r]+b_hh[r];
          r=2*256+ 64+lane; b5=b_ih[r]+b_hh[r]; }
#pragma unroll
        for (int g=0; g<4; ++g){
            const float* src = W_ih_rest + ((size_t)2*256 + g*64+lane)*64;
#pragma unroll
            for (int d=0; d<8; ++d) *(uint4*)&s_wih[2+g][d][lane][0] = pack8(src + 8*d);
        }
        { int r;
          r=3*256+  0+lane; b6=b_ih[r]+b_hh[r];
          r=3*256+ 64+lane; b7=b_ih[r]+b_hh[r];
          r=3*256+128+lane; b8=b_ih[r]+b_hh[r];
          r=3*256+192+lane; b9=b_ih[r]+b_hh[r]; }
    }
    __syncthreads();

// ---- recurrence step, no-lo, even/odd-d split chains (8 chains) ----
#define R_STEPN(L, WB, LASTF, T, C, CST) do{                                   \
    const int buf_ = (C)&1;                                                    \
    float xi_ = __half2float(s_xg[buf_][L][T][      lane]);                    \
    float xf_ = __half2float(s_xg[buf_][L][T][ 64 + lane]);                    \
    float xgg_= __half2float(s_xg[buf_][L][T][128 + lane]);                    \
    float xo_ = __half2float(s_xg[buf_][L][T][192 + lane]);                    \
    float ai0=0,ai1=0, af0=0,af1=0, ag0=0,ag1=0, ao0=0,ao1=0;                  \
    _Pragma("unroll")                                                          \
    for (int d_=0; d_<8; d_+=2){                                               \
        uint4 h0_ = *(const uint4*)&s_h16[L][4*d_];                            \
        uint4 h1_ = *(const uint4*)&s_h16[L][4*d_+4];                          \
        uint4 woA_ = *(const uint4*)&s_wo[L][d_  ][lane][0];                   \
        uint4 woB_ = *(const uint4*)&s_wo[L][d_+1][lane][0];                   \
        DOT4(ai0, wU[(WB)+d_],      h0_); DOT4(ai1, wU[(WB)+d_+1],    h1_);    \
        DOT4(af0, wU[(WB)+8+d_],    h0_); DOT4(af1, wU[(WB)+8+d_+1],  h1_);    \
        DOT4(ag0, wU[(WB)+16+d_],   h0_); DOT4(ag1, wU[(WB)+16+d_+1], h1_);    \
        DOT4(ao0, woA_,             h0_); DOT4(ao1, woB_,             h1_);    \
    }                                                                          \
    float I_=sigmoid_(xi_+(ai0+ai1)), F_=sigmoid_(xf_+(af0+af1));              \
    float G_=tanh_(xgg_+(ag0+ag1)),   O_=sigmoid_(xo_+(ao0+ao1));              \
    CST = fmaf(F_, CST, I_*G_);                                                \
    float h_ = O_*tanh_(CST);                                                  \
    __half hhi_=__float2half(h_);                                              \
    ((__half*)&s_h16[L][0])[lane]=hhi_;                                        \
    if (!(LASTF)){                                                             \
        ((__half*)&s_hh[(L)<4?(L):0][buf_][T][0])[lane]=hhi_;                  \
    } else if ((C)==NCH-1 && (T)==CH-1){ hlast_g[lane]=h_; }                   \
}while(0)

// ---- G tile: 2 gate-row groups x 4 timesteps; weights read once ----
// HB: uint* base of h source (t-stride HSTR uints); XB: __half* xg dest [CH][256]
#define G2Q(DMAX, WEXPR, HB, HSTR, XB, ROWOFF, B0_,B1_) do{                    \
    float a00=(B0_),a01=(B0_),a02=(B0_),a03=(B0_);                             \
    float a10=(B1_),a11=(B1_),a12=(B1_),a13=(B1_);                             \
    _Pragma("unroll")                                                          \
    for (int d_=0; d_<(DMAX); ++d_){                                           \
        uint4 wa_ = WEXPR(0,d_), wb_ = WEXPR(1,d_);                            \
        uint4 h0_=*(const uint4*)&(HB)[0*(HSTR)+4*d_];                         \
        uint4 h1_=*(const uint4*)&(HB)[1*(HSTR)+4*d_];                         \
        uint4 h2_=*(const uint4*)&(HB)[2*(HSTR)+4*d_];                         \
        uint4 h3_=*(const uint4*)&(HB)[3*(HSTR)+4*d_];                         \
        DOT4(a00,wa_,h0_); DOT4(a01,wa_,h1_); DOT4(a02,wa_,h2_); DOT4(a03,wa_,h3_);\
        DOT4(a10,wb_,h0_); DOT4(a11,wb_,h1_); DOT4(a12,wb_,h2_); DOT4(a13,wb_,h3_);\
    }                                                                          \
    __half* xp_ = (__half*)(XB);                                               \
    xp_[0*256+(ROWOFF)+lane]=__float2half(a00);                                \
    xp_[1*256+(ROWOFF)+lane]=__float2half(a01);                                \
    xp_[2*256+(ROWOFF)+lane]=__float2half(a02);                                \
    xp_[3*256+(ROWOFF)+lane]=__float2half(a03);                                \
    xp_[0*256+(ROWOFF)+64+lane]=__float2half(a10);                             \
    xp_[1*256+(ROWOFF)+64+lane]=__float2half(a11);                             \
    xp_[2*256+(ROWOFF)+64+lane]=__float2half(a12);                             \
    xp_[3*256+(ROWOFF)+64+lane]=__float2half(a13);                             \
}while(0)

// weight selectors (g is the local 0/1 row-group of a tile)
#define W_L1A(g,d) wU[(g)*8+(d)]
#define W_L1B(g,d) wU[(2+(g))*8+(d)]
#define W_L2R(g,d) wU[32+(g)*8+(d)]
#define W_L0A(g,d) wU[24+(g)*6+(d)]
#define W_L0B(g,d) wU[24+(2+(g))*6+(d)]
#define W_L2L(g,d) (*(const uint4*)&s_wih[(g)][d][lane][0])
#define W_L3A(g,d) (*(const uint4*)&s_wih[2+(g)][d][lane][0])
#define W_L3B(g,d) (*(const uint4*)&s_wih[4+(g)][d][lane][0])
#define W_L4A(g,d) (*(const uint4*)&s_wih[6+(g)][d][lane][0])
#define W_L4B(g,d) (*(const uint4*)&s_wih[8+(g)][d][lane][0])

#define STAGE_X() do{                                                          \
    const int bufx = k & 1;                                                    \
    _Pragma("unroll")                                                          \
    for (int r=0; r<3; ++r){                                                   \
        const int i = lane + 64*r;                                             \
        if (i < CH*45){                                                        \
            float v = x_s[(size_t)k*(CH*45) + i];                              \
            const int t = i/45, d = i - 45*t;                                  \
            ((__half*)&s_x[bufx][t][0])[d] = __float2half(v);                  \
        }                                                                      \
    }                                                                          \
}while(0)

// per-wave supercycle bodies (GUARDED=1 only in prologue/epilogue)
#define BODY_W0(GUARDED) do{                                                   \
    const int c0=k-2, c1=k-4, cl=k-9;                                          \
    if (!(GUARDED) || (c0>=0 && c0<NCH)){ R_STEPN(0,  0, 0, 0, c0, cA); }      \
    if (!(GUARDED) || (c1>=0 && c1<NCH)){ R_STEPN(1, 24, 0, 0, c1, cB); }      \
    if (!(GUARDED) || (c0>=0 && c0<NCH)){ R_STEPN(0,  0, 0, 1, c0, cA); }      \
    if (!(GUARDED) || (c1>=0 && c1<NCH)){ R_STEPN(1, 24, 0, 1, c1, cB); }      \
    if (!(GUARDED) || (c0>=0 && c0<NCH)){ R_STEPN(0,  0, 0, 2, c0, cA); }      \
    if (!(GUARDED) || (c1>=0 && c1<NCH)){ R_STEPN(1, 24, 0, 2, c1, cB); }      \
    if (!(GUARDED) || (c0>=0 && c0<NCH)){ R_STEPN(0,  0, 0, 3, c0, cA); }      \
    if (!(GUARDED) || (c1>=0 && c1<NCH)){ R_STEPN(1, 24, 0, 3, c1, cB); }      \
    if (!(GUARDED) || (cl>=0 && cl<NCH)){                                      \
        const int bl=cl&1;                                                     \
        G2Q(8, W_L4A, (&s_hh[3][bl][0][0]), 32,                                \
            (&s_xg[bl][4][0][0]), 0, b0,b1); }                                 \
}while(0)

#define BODY_W1(GUARDED) do{                                                   \
    const int c2=k-6, c3=k-8, cl=k-9;                                          \
    if (!(GUARDED) || (c2>=0 && c2<NCH)){ R_STEPN(2,  0, 0, 0, c2, cA); }      \
    if (!(GUARDED) || (c3>=0 && c3<NCH)){ R_STEPN(3, 24, 0, 0, c3, cB); }      \
    if (!(GUARDED) || (c2>=0 && c2<NCH)){ R_STEPN(2,  0, 0, 1, c2, cA); }      \
    if (!(GUARDED) || (c3>=0 && c3<NCH)){ R_STEPN(3, 24, 0, 1, c3, cB); }      \
    if (!(GUARDED) || (c2>=0 && c2<NCH)){ R_STEPN(2,  0, 0, 2, c2, cA); }      \
    if (!(GUARDED) || (c3>=0 && c3<NCH)){ R_STEPN(3, 24, 0, 2, c3, cB); }      \
    if (!(GUARDED) || (c2>=0 && c2<NCH)){ R_STEPN(2,  0, 0, 3, c2, cA); }      \
    if (!(GUARDED) || (c3>=0 && c3<NCH)){ R_STEPN(3, 24, 0, 3, c3, cB); }      \
    if (!(GUARDED) || (cl>=0 && cl<NCH)){                                      \
        const int bl=cl&1;                                                     \
        G2Q(8, W_L4B, (&s_hh[3][bl][0][0]), 32,                                \
            (&s_xg[bl][4][0][0]), 128, b0,b1); }                               \
}while(0)

#define BODY_W2(GUARDED) do{                                                   \
    if (!(GUARDED) || (k < NCH)) STAGE_X();                                    \
    const int c4=k-10, cg0=k-1, cg2=k-5;                                       \
    if (!(GUARDED) || (c4>=0 && c4<NCH)){ R_STEPN(4, 0, 1, 0, c4, cA); }       \
    if (!(GUARDED) || (c4>=0 && c4<NCH)){ R_STEPN(4, 0, 1, 1, c4, cA); }       \
    if (!(GUARDED) || (cg0>=0 && cg0<NCH)){                                    \
        const int bg=cg0&1;                                                    \
        G2Q(6, W_L0A, (&s_x[bg][0][0]), 24,                                    \
            (&s_xg[bg][0][0][0]), 0, b0,b1); }                                 \
    if (!(GUARDED) || (c4>=0 && c4<NCH)){ R_STEPN(4, 0, 1, 2, c4, cA); }       \
    if (!(GUARDED) || (c4>=0 && c4<NCH)){ R_STEPN(4, 0, 1, 3, c4, cA); }       \
    if (!(GUARDED) || (cg0>=0 && cg0<NCH)){                                    \
        const int bg=cg0&1;                                                    \
        G2Q(6, W_L0B, (&s_x[bg][0][0]), 24,                                    \
            (&s_xg[bg][0][0][0]), 128, b2,b3); }                               \
    if (!(GUARDED) || (cg2>=0 && cg2<NCH)){                                    \
        const int bg=cg2&1;                                                    \
        G2Q(8, W_L2L, (&s_hh[1][bg][0][0]), 32,                                \
            (&s_xg[bg][2][0][0]), 128, b4,b5); }                               \
}while(0)

#define BODY_W3(GUARDED) do{                                                   \
    const int cg1=k-3, cg2=k-5, cg3=k-7;                                       \
    if (!(GUARDED) || (cg1>=0 && cg1<NCH)){                                    \
        const int bg=cg1&1;                                                    \
        G2Q(8, W_L1A, (&s_hh[0][bg][0][0]), 32,                                \
            (&s_xg[bg][1][0][0]), 0, b0,b1);                                   \
        G2Q(8, W_L1B, (&s_hh[0][bg][0][0]), 32,                                \
            (&s_xg[bg][1][0][0]), 128, b2,b3); }                               \
    if (!(GUARDED) || (cg2>=0 && cg2<NCH)){                                    \
        const int bg=cg2&1;                                                    \
        G2Q(8, W_L2R, (&s_hh[1][bg][0][0]), 32,                                \
            (&s_xg[bg][2][0][0]), 0, b4,b5); }                                 \
    if (!(GUARDED) || (cg3>=0 && cg3<NCH)){                                    \
        const int bg=cg3&1;                                                    \
        G2Q(8, W_L3A, (&s_hh[2][bg][0][0]), 32,                                \
            (&s_xg[bg][3][0][0]), 0, b6,b7);                                   \
        G2Q(8, W_L3B, (&s_hh[2][bg][0][0]), 32,                                \
            (&s_xg[bg][3][0][0]), 128, b8,b9); }                               \
}while(0)

    // ================= supercycle loop =================
    for (int k=0; k<KMAX; ++k){
        if (k >= 10 && k < NCH){
            if      (wave == 0) BODY_W0(0);
            else if (wave == 1) BODY_W1(0);
            else if (wave == 2) BODY_W2(0);
            else                BODY_W3(0);
        } else {
            if      (wave == 0) BODY_W0(1);
            else if (wave == 1) BODY_W1(1);
            else if (wave == 2) BODY_W2(1);
            else                BODY_W3(1);
        }
        __syncthreads();
    }
}

// MLP head: features = gelu(last @ Wl^T + bl); out = relu(features @ Wo^T + bo)
// d_out layout: out[256*4] first, then features[256*128].
__global__ __launch_bounds__(128)
void head_kernel(const float* __restrict__ h_last,  // [256, 64]
                 const float* __restrict__ Wl,      // [128, 64]
                 const float* __restrict__ bl,      // [128]
                 const float* __restrict__ Wo,      // [4, 128]
                 const float* __restrict__ bo,      // [4]
                 float* __restrict__ d_out)
{
    __shared__ float s_last[HID];
    __shared__ float s_feat[128];
    const int s = blockIdx.x;
    const int j = threadIdx.x;

    if (j < HID) s_last[j] = h_last[(size_t)s * HID + j];
    __syncthreads();

    float acc = bl[j];
#pragma unroll
    for (int k = 0; k < HID; ++k)
        acc = fmaf(s_last[k], Wl[j * HID + k], acc);
    float f = 0.5f * acc * (1.0f + erff(acc * 0.70710678118654752440f));
    d_out[256 * 4 + s * 128 + j] = f;
    s_feat[j] = f;
    __syncthreads();

    if (j < 4) {
        float a = bo[j];
#pragma unroll
        for (int k = 0; k < 128; ++k)
            a = fmaf(s_feat[k], Wo[j * 128 + k], a);
        d_out[s * 4 + j] = fmaxf(a, 0.0f);
    }
}

extern "C" void kernel_launch(void* const* d_in, const int* in_sizes, int n_in,
                              void* d_out, int out_size, void* d_ws, size_t ws_size,
                              hipStream_t stream)
{
    const float* x         = (const float*)d_in[0];  // [256, 2048, 45]
    const float* W_ih0     = (const float*)d_in[1];  // [256, 45]
    const float* W_ih_rest = (const float*)d_in[2];  // [4, 256, 64]
    const float* W_hh      = (const float*)d_in[3];  // [5, 256, 64]
    const float* b_ih      = (const float*)d_in[4];  // [5, 256]
    const float* b_hh      = (const float*)d_in[5];  // [5, 256]
    const float* Wl        = (const float*)d_in[6];  // [128, 64]
    const float* bl        = (const float*)d_in[7];  // [128]
    const float* Wo        = (const float*)d_in[8];  // [4, 128]
    const float* bo        = (const float*)d_in[9];  // [4]

    float* h_last = (float*)d_ws;   // [256, 64] fp32

    lstm_pipe4<<<256, 256, 0, stream>>>(
        x, W_ih0, W_ih_rest, W_hh, b_ih, b_hh, h_last);
    head_kernel<<<256, 128, 0, stream>>>(h_last, Wl, bl, Wo, bo, (float*)d_out);
}

// Round 14
// 10411.333 us; speedup vs baseline: 1.6427x; 1.3884x over previous
//
#include <hip/hip_runtime.h>
#include <hip/hip_fp16.h>
#include <math.h>

#define CH    4
#define NCH   512             // 2048 timesteps / CH
#define KMAX  522             // last event: R4 chunk 511 at k = 511+10
#define HID   64
typedef unsigned int uint;
typedef __attribute__((ext_vector_type(2))) _Float16 h2t;

__device__ __forceinline__ float sigmoid_(float x){ return 1.0f/(1.0f+__expf(-x)); }
__device__ __forceinline__ float tanh_(float x){ float e=__expf(2.0f*x); return 1.0f-2.0f/(e+1.0f); }

__device__ __forceinline__ float fdot2_(uint w, uint h, float acc){
#if __has_builtin(__builtin_amdgcn_fdot2)
    return __builtin_amdgcn_fdot2(__builtin_bit_cast(h2t,w), __builtin_bit_cast(h2t,h), acc, false);
#else
    __half2 wv = *reinterpret_cast<const __half2*>(&w);
    __half2 hv = *reinterpret_cast<const __half2*>(&h);
    float2 wf = __half22float2(wv), hf = __half22float2(hv);
    return fmaf(wf.x, hf.x, fmaf(wf.y, hf.y, acc));
#endif
}
__device__ __forceinline__ uint packh(float a, float b){
    uint ha = (uint)__half_as_ushort(__float2half(a));   // RNE
    uint hb = (uint)__half_as_ushort(__float2half(b));
    return (hb<<16)|ha;
}
__device__ __forceinline__ uint4 pack8(const float* p){
    return make_uint4(packh(p[0],p[1]), packh(p[2],p[3]), packh(p[4],p[5]), packh(p[6],p[7]));
}

#define DOT4(A, W, H) do{ \
    A=fdot2_((W).x,(H).x,A); A=fdot2_((W).y,(H).y,A); \
    A=fdot2_((W).z,(H).z,A); A=fdot2_((W).w,(H).w,A); }while(0)

// All 5 LSTM layers, wavefront-pipelined, ONE kernel.
// grid = 256 blocks (1 sample), block = 256 threads (4 waves; VGPR cap law
// cap = 65536/block_threads -> 256. r9/r11: ~250 = no spill; r10/r13: full
// unroll of 4-timestep bodies -> spill. So: CH=4 with RUNTIME unroll-1 R
// loops (transients die per iteration) and lean G tiles).
// Round-14 = r13's validated CH=4 schedule + r11's weight distribution:
//   w0: R L0+L1 (t-loop) + xg[L4] rows 0-127 via G1Q (LDS W, read 1x/4t)
//   w1: R L2+L3 (t-loop) + xg[L4] rows 128-255 via G1Q
//   w2: R L4 (t-loop) + stage x + xg[L0] (reg W, G4T x2) + xg[L2] rows 128-255 via G1Q
//   w3: xg[L1] (reg W, G4T x2) + xg[L2] rows 0-127 (reg W, G2T x2) + xg[L3] via G1Q x4
// xg fp16 (validated r13: absmax unchanged). 522 supercycles, 1 barrier each.
// stage x(c)@k=c; G_l(c)@k=c+1+2l; R_l(c)@k=c+2+2l.
__global__ __attribute__((amdgpu_waves_per_eu(1,1))) __launch_bounds__(256)
void lstm_pipe4(const float* __restrict__ x,          // [256,2048,45]
                const float* __restrict__ W_ih0,      // [256,45]
                const float* __restrict__ W_ih_rest,  // [4,256,64]
                const float* __restrict__ W_hh,       // [5,256,64]
                const float* __restrict__ b_ih,       // [5,256]
                const float* __restrict__ b_hh,       // [5,256]
                float* __restrict__ h_last)           // [256,64] (d_ws)
{
    __shared__ __half s_xg[2][5][CH][256];      // 20480 B  xg double buffer (fp16)
    __shared__ uint  s_wo [5][8][64][4];        // 40960 B  W_hh o-gate, fp16 packed
    __shared__ uint  s_wih[10][8][64][4];       // 81920 B  W_ih groups, fp16 packed
    __shared__ uint  s_hh[4][2][CH][32];        //  4096 B  h handoff (fp16)
    __shared__ uint  s_h16[5][32];              //   640 B  per-layer running h (fp16)
    __shared__ uint  s_x[2][CH][24];            //   768 B  staged x chunk (fp16, 45+3 pad)
    // total 148864 B -> 1 block/CU

    const int tid  = threadIdx.x;
    const int wave = tid >> 6;
    const int lane = tid & 63;
    const int sm   = blockIdx.x;
    const float* x_s = x + (size_t)sm * 2048 * 45;
    float* hlast_g = h_last + (size_t)sm * HID;

    uint4 wU[48];          // per-wave weight register file (192 dwords), static-indexed
    float b0=0,b1=0,b2=0,b3=0,b4=0,b5=0,b6=0,b7=0,b8=0,b9=0;
    float cA=0.f, cB=0.f;  // cell states

    // ================= init: pack weights, stage LDS (r9/r11/r13-verified) =================
    if (wave == 0 || wave == 1){
#pragma unroll
        for (int li=0; li<2; ++li){
            const int L = wave*2 + li;
            const float* base = W_hh + (size_t)L*256*64;
#pragma unroll
            for (int d=0; d<8; ++d){
                wU[li*24 + 0*8 + d] = pack8(base + (size_t)(  0+lane)*64 + 8*d);  // i
                wU[li*24 + 1*8 + d] = pack8(base + (size_t)( 64+lane)*64 + 8*d);  // f
                wU[li*24 + 2*8 + d] = pack8(base + (size_t)(128+lane)*64 + 8*d);  // g
                *(uint4*)&s_wo[L][d][lane][0] = pack8(base + (size_t)(192+lane)*64 + 8*d); // o
            }
            if (lane<32) s_h16[L][lane]=0u;
        }
#pragma unroll
        for (int g=0; g<2; ++g){
            const int row = wave*128 + g*64 + lane;
            const float* src = W_ih_rest + ((size_t)3*256 + row)*64;
            const int grp = 6 + wave*2 + g;
#pragma unroll
            for (int d=0; d<8; ++d)
                *(uint4*)&s_wih[grp][d][lane][0] = pack8(src + 8*d);
        }
        { int r0 = 4*256 + wave*128 + lane, r1 = r0 + 64;
          b0 = b_ih[r0]+b_hh[r0]; b1 = b_ih[r1]+b_hh[r1]; }
    } else if (wave == 2){
        const float* base = W_hh + (size_t)4*256*64;
#pragma unroll
        for (int d=0; d<8; ++d){
            wU[0*8+d] = pack8(base + (size_t)(  0+lane)*64 + 8*d);
            wU[1*8+d] = pack8(base + (size_t)( 64+lane)*64 + 8*d);
            wU[2*8+d] = pack8(base + (size_t)(128+lane)*64 + 8*d);
            *(uint4*)&s_wo[4][d][lane][0] = pack8(base + (size_t)(192+lane)*64 + 8*d);
        }
        if (lane<32) s_h16[4][lane]=0u;
#pragma unroll
        for (int g=0; g<4; ++g){
            const float* src = W_ih0 + (size_t)(g*64+lane)*45;
#pragma unroll
            for (int d=0; d<6; ++d){
                float e0=(8*d+0<45)?src[8*d+0]:0.f, e1=(8*d+1<45)?src[8*d+1]:0.f;
                float e2=(8*d+2<45)?src[8*d+2]:0.f, e3=(8*d+3<45)?src[8*d+3]:0.f;
                float e4=(8*d+4<45)?src[8*d+4]:0.f, e5=(8*d+5<45)?src[8*d+5]:0.f;
                float e6=(8*d+6<45)?src[8*d+6]:0.f, e7=(8*d+7<45)?src[8*d+7]:0.f;
                wU[24 + g*6 + d] = make_uint4(packh(e0,e1),packh(e2,e3),packh(e4,e5),packh(e6,e7));
            }
        }
        { int r;
          r=      lane; b0=b_ih[r]+b_hh[r];
          r=  64+lane;  b1=b_ih[r]+b_hh[r];
          r= 128+lane;  b2=b_ih[r]+b_hh[r];
          r= 192+lane;  b3=b_ih[r]+b_hh[r]; }
#pragma unroll
        for (int g=0; g<2; ++g){
            const int row = 128 + g*64 + lane;
            const float* src = W_ih_rest + ((size_t)1*256 + row)*64;
#pragma unroll
            for (int d=0; d<8; ++d)
                *(uint4*)&s_wih[g][d][lane][0] = pack8(src + 8*d);
        }
        { int r0=2*256+128+lane, r1=2*256+192+lane;
          b4=b_ih[r0]+b_hh[r0]; b5=b_ih[r1]+b_hh[r1]; }
        // zero x pad halves (cols 45..47, all buf/t)
        if (lane < 2*CH*3){
            int bb=lane/(CH*3), rem=lane%(CH*3), t=rem/3, d=45+rem%3;
            ((__half*)&s_x[bb][t][0])[d]=__float2half(0.f);
        }
    } else { // wave 3
#pragma unroll
        for (int g=0; g<6; ++g){
            const int ly  = (g<4) ? 1 : 2;
            const int row = (g<4) ? g*64+lane : (g-4)*64+lane;
            const float* src = W_ih_rest + ((size_t)(ly-1)*256 + row)*64;
#pragma unroll
            for (int d=0; d<8; ++d) wU[g*8+d] = pack8(src + 8*d);
        }
        { int r;
          r=1*256+  0+lane; b0=b_ih[r]+b_hh[r];
          r=1*256+ 64+lane; b1=b_ih[r]+b_hh[r];
          r=1*256+128+lane; b2=b_ih[r]+b_hh[r];
          r=1*256+192+lane; b3=b_ih[r]+b_hh[r];
          r=2*256+  0+lane; b4=b_ih[r]+b_hh[r];
          r=2*256+ 64+lane; b5=b_ih[r]+b_hh[r]; }
#pragma unroll
        for (int g=0; g<4; ++g){
            const float* src = W_ih_rest + ((size_t)2*256 + g*64+lane)*64;
#pragma unroll
            for (int d=0; d<8; ++d) *(uint4*)&s_wih[2+g][d][lane][0] = pack8(src + 8*d);
        }
        { int r;
          r=3*256+  0+lane; b6=b_ih[r]+b_hh[r];
          r=3*256+ 64+lane; b7=b_ih[r]+b_hh[r];
          r=3*256+128+lane; b8=b_ih[r]+b_hh[r];
          r=3*256+192+lane; b9=b_ih[r]+b_hh[r]; }
    }
    __syncthreads();

// ---- recurrence step, no-lo, even/odd-d split chains; T may be runtime ----
#define R_STEPN(L, WB, LASTF, T, C, CST) do{                                   \
    const int buf_ = (C)&1;                                                    \
    float xi_ = __half2float(s_xg[buf_][L][T][      lane]);                    \
    float xf_ = __half2float(s_xg[buf_][L][T][ 64 + lane]);                    \
    float xgg_= __half2float(s_xg[buf_][L][T][128 + lane]);                    \
    float xo_ = __half2float(s_xg[buf_][L][T][192 + lane]);                    \
    float ai0=0,ai1=0, af0=0,af1=0, ag0=0,ag1=0, ao0=0,ao1=0;                  \
    _Pragma("unroll")                                                          \
    for (int d_=0; d_<8; d_+=2){                                               \
        uint4 h0_ = *(const uint4*)&s_h16[L][4*d_];                            \
        uint4 h1_ = *(const uint4*)&s_h16[L][4*d_+4];                          \
        uint4 woA_ = *(const uint4*)&s_wo[L][d_  ][lane][0];                   \
        uint4 woB_ = *(const uint4*)&s_wo[L][d_+1][lane][0];                   \
        DOT4(ai0, wU[(WB)+d_],      h0_); DOT4(ai1, wU[(WB)+d_+1],    h1_);    \
        DOT4(af0, wU[(WB)+8+d_],    h0_); DOT4(af1, wU[(WB)+8+d_+1],  h1_);    \
        DOT4(ag0, wU[(WB)+16+d_],   h0_); DOT4(ag1, wU[(WB)+16+d_+1], h1_);    \
        DOT4(ao0, woA_,             h0_); DOT4(ao1, woB_,             h1_);    \
    }                                                                          \
    float I_=sigmoid_(xi_+(ai0+ai1)), F_=sigmoid_(xf_+(af0+af1));              \
    float G_=tanh_(xgg_+(ag0+ag1)),   O_=sigmoid_(xo_+(ao0+ao1));              \
    CST = fmaf(F_, CST, I_*G_);                                                \
    float h_ = O_*tanh_(CST);                                                  \
    __half hhi_=__float2half(h_);                                              \
    ((__half*)&s_h16[L][0])[lane]=hhi_;                                        \
    if (!(LASTF)){                                                             \
        ((__half*)&s_hh[(L)<4?(L):0][buf_][T][0])[lane]=hhi_;                  \
    } else if ((C)==NCH-1 && (T)==CH-1){ hlast_g[lane]=h_; }                   \
}while(0)

// ---- G1Q: 1 row-group x 4 timesteps, LDS weights read ONCE per chunk ----
// (lean: 4 accums + 1 w + 4 h uint4 ~ 36 live regs)
#define G1Q(DMAX, WEXPR, HB, HSTR, XB, ROWOFF, B0_) do{                        \
    float a0=(B0_),a1=(B0_),a2=(B0_),a3=(B0_);                                 \
    _Pragma("unroll")                                                          \
    for (int d_=0; d_<(DMAX); ++d_){                                           \
        uint4 w_ = WEXPR(d_);                                                  \
        uint4 h0_=*(const uint4*)&(HB)[0*(HSTR)+4*d_];                         \
        uint4 h1_=*(const uint4*)&(HB)[1*(HSTR)+4*d_];                         \
        uint4 h2_=*(const uint4*)&(HB)[2*(HSTR)+4*d_];                         \
        uint4 h3_=*(const uint4*)&(HB)[3*(HSTR)+4*d_];                         \
        DOT4(a0,w_,h0_); DOT4(a1,w_,h1_); DOT4(a2,w_,h2_); DOT4(a3,w_,h3_);    \
    }                                                                          \
    __half* xp_ = (__half*)(XB);                                               \
    xp_[0*256+(ROWOFF)+lane]=__float2half(a0);                                 \
    xp_[1*256+(ROWOFF)+lane]=__float2half(a1);                                 \
    xp_[2*256+(ROWOFF)+lane]=__float2half(a2);                                 \
    xp_[3*256+(ROWOFF)+lane]=__float2half(a3);                                 \
}while(0)

// ---- G4T: 4 row-groups x 2 timesteps, REGISTER weights (re-read free) ----
#define G4T(DMAX, WEXPR, H0, H1, XD0, XD1, B0_,B1_,B2_,B3_) do{                \
    float a00=(B0_),a01=(B1_),a02=(B2_),a03=(B3_);                             \
    float a10=(B0_),a11=(B1_),a12=(B2_),a13=(B3_);                             \
    _Pragma("unroll")                                                          \
    for (int d_=0; d_<(DMAX); ++d_){                                           \
        uint4 w0_=WEXPR(0,d_), w1_=WEXPR(1,d_), w2_=WEXPR(2,d_), w3_=WEXPR(3,d_);\
        uint4 h0_=*(const uint4*)&(H0)[4*d_];                                  \
        uint4 h1_=*(const uint4*)&(H1)[4*d_];                                  \
        DOT4(a00,w0_,h0_); DOT4(a01,w1_,h0_); DOT4(a02,w2_,h0_); DOT4(a03,w3_,h0_);\
        DOT4(a10,w0_,h1_); DOT4(a11,w1_,h1_); DOT4(a12,w2_,h1_); DOT4(a13,w3_,h1_);\
    }                                                                          \
    __half* xp0_ = (__half*)(XD0);                                             \
    __half* xp1_ = (__half*)(XD1);                                             \
    xp0_[      lane]=__float2half(a00); xp0_[ 64+lane]=__float2half(a01);      \
    xp0_[128+lane]=__float2half(a02);   xp0_[192+lane]=__float2half(a03);      \
    xp1_[      lane]=__float2half(a10); xp1_[ 64+lane]=__float2half(a11);      \
    xp1_[128+lane]=__float2half(a12);   xp1_[192+lane]=__float2half(a13);      \
}while(0)

// ---- G2T: 2 row-groups x 2 timesteps, REGISTER weights ----
#define G2T(DMAX, WEXPR, H0, H1, XD0, XD1, ROWOFF, B0_,B1_) do{                \
    float a00=(B0_),a01=(B1_), a10=(B0_),a11=(B1_);                            \
    _Pragma("unroll")                                                          \
    for (int d_=0; d_<(DMAX); ++d_){                                           \
        uint4 wa_ = WEXPR(0,d_), wb_ = WEXPR(1,d_);                            \
        uint4 h0_=*(const uint4*)&(H0)[4*d_];                                  \
        uint4 h1_=*(const uint4*)&(H1)[4*d_];                                  \
        DOT4(a00,wa_,h0_); DOT4(a01,wb_,h0_);                                  \
        DOT4(a10,wa_,h1_); DOT4(a11,wb_,h1_);                                  \
    }                                                                          \
    __half* xp0_ = (__half*)(XD0);                                             \
    __half* xp1_ = (__half*)(XD1);                                             \
    xp0_[(ROWOFF)+lane]=__float2half(a00); xp0_[(ROWOFF)+64+lane]=__float2half(a01);\
    xp1_[(ROWOFF)+lane]=__float2half(a10); xp1_[(ROWOFF)+64+lane]=__float2half(a11);\
}while(0)

// weight selectors
#define W_L1(g,d)  wU[(g)*8+(d)]
#define W_L2R(g,d) wU[32+(g)*8+(d)]
#define W_L0(g,d)  wU[24+(g)*6+(d)]
#define WL2_0(d) (*(const uint4*)&s_wih[0][d][lane][0])
#define WL2_1(d) (*(const uint4*)&s_wih[1][d][lane][0])
#define WL3_0(d) (*(const uint4*)&s_wih[2][d][lane][0])
#define WL3_1(d) (*(const uint4*)&s_wih[3][d][lane][0])
#define WL3_2(d) (*(const uint4*)&s_wih[4][d][lane][0])
#define WL3_3(d) (*(const uint4*)&s_wih[5][d][lane][0])
#define WL4_0(d) (*(const uint4*)&s_wih[6][d][lane][0])
#define WL4_1(d) (*(const uint4*)&s_wih[7][d][lane][0])
#define WL4_2(d) (*(const uint4*)&s_wih[8][d][lane][0])
#define WL4_3(d) (*(const uint4*)&s_wih[9][d][lane][0])

#define STAGE_X() do{                                                          \
    const int bufx = k & 1;                                                    \
    _Pragma("unroll")                                                          \
    for (int r=0; r<3; ++r){                                                   \
        const int i = lane + 64*r;                                             \
        if (i < CH*45){                                                        \
            float v = x_s[(size_t)k*(CH*45) + i];                              \
            const int t = i/45, d = i - 45*t;                                  \
            ((__half*)&s_x[bufx][t][0])[d] = __float2half(v);                  \
        }                                                                      \
    }                                                                          \
}while(0)

// per-wave supercycle bodies (GUARDED=1 only in prologue/epilogue)
#define BODY_W0(GUARDED) do{                                                   \
    const int c0=k-2, c1=k-4, cl=k-9;                                          \
    _Pragma("unroll 1")                                                        \
    for (int t=0; t<CH; ++t){                                                  \
        if (!(GUARDED) || (c0>=0 && c0<NCH)){ R_STEPN(0,  0, 0, t, c0, cA); }  \
        if (!(GUARDED) || (c1>=0 && c1<NCH)){ R_STEPN(1, 24, 0, t, c1, cB); }  \
    }                                                                          \
    if (!(GUARDED) || (cl>=0 && cl<NCH)){                                      \
        const int bl=cl&1;                                                     \
        G1Q(8, WL4_0, (&s_hh[3][bl][0][0]), 32, (&s_xg[bl][4][0][0]),  0, b0); \
        G1Q(8, WL4_1, (&s_hh[3][bl][0][0]), 32, (&s_xg[bl][4][0][0]), 64, b1); \
    }                                                                          \
}while(0)

#define BODY_W1(GUARDED) do{                                                   \
    const int c2=k-6, c3=k-8, cl=k-9;                                          \
    _Pragma("unroll 1")                                                        \
    for (int t=0; t<CH; ++t){                                                  \
        if (!(GUARDED) || (c2>=0 && c2<NCH)){ R_STEPN(2,  0, 0, t, c2, cA); }  \
        if (!(GUARDED) || (c3>=0 && c3<NCH)){ R_STEPN(3, 24, 0, t, c3, cB); }  \
    }                                                                          \
    if (!(GUARDED) || (cl>=0 && cl<NCH)){                                      \
        const int bl=cl&1;                                                     \
        G1Q(8, WL4_2, (&s_hh[3][bl][0][0]), 32, (&s_xg[bl][4][0][0]), 128, b0);\
        G1Q(8, WL4_3, (&s_hh[3][bl][0][0]), 32, (&s_xg[bl][4][0][0]), 192, b1);\
    }                                                                          \
}while(0)

#define BODY_W2(GUARDED) do{                                                   \
    if (!(GUARDED) || (k < NCH)) STAGE_X();                                    \
    const int c4=k-10, cg0=k-1, cg2=k-5;                                       \
    _Pragma("unroll 1")                                                        \
    for (int t=0; t<CH; ++t){                                                  \
        if (!(GUARDED) || (c4>=0 && c4<NCH)){ R_STEPN(4, 0, 1, t, c4, cA); }   \
    }                                                                          \
    if (!(GUARDED) || (cg0>=0 && cg0<NCH)){                                    \
        const int bg=cg0&1;                                                    \
        G4T(6, W_L0, (&s_x[bg][0][0]), (&s_x[bg][1][0]),                       \
            (&s_xg[bg][0][0][0]), (&s_xg[bg][0][1][0]), b0,b1,b2,b3);          \
        G4T(6, W_L0, (&s_x[bg][2][0]), (&s_x[bg][3][0]),                       \
            (&s_xg[bg][0][2][0]), (&s_xg[bg][0][3][0]), b0,b1,b2,b3);          \
    }                                                                          \
    if (!(GUARDED) || (cg2>=0 && cg2<NCH)){                                    \
        const int bg=cg2&1;                                                    \
        G1Q(8, WL2_0, (&s_hh[1][bg][0][0]), 32, (&s_xg[bg][2][0][0]), 128, b4);\
        G1Q(8, WL2_1, (&s_hh[1][bg][0][0]), 32, (&s_xg[bg][2][0][0]), 192, b5);\
    }                                                                          \
}while(0)

#define BODY_W3(GUARDED) do{                                                   \
    const int cg1=k-3, cg2=k-5, cg3=k-7;                                       \
    if (!(GUARDED) || (cg1>=0 && cg1<NCH)){                                    \
        const int bg=cg1&1;                                                    \
        G4T(8, W_L1, (&s_hh[0][bg][0][0]), (&s_hh[0][bg][1][0]),               \
            (&s_xg[bg][1][0][0]), (&s_xg[bg][1][1][0]), b0,b1,b2,b3);          \
        G4T(8, W_L1, (&s_hh[0][bg][2][0]), (&s_hh[0][bg][3][0]),               \
            (&s_xg[bg][1][2][0]), (&s_xg[bg][1][3][0]), b0,b1,b2,b3);          \
    }                                                                          \
    if (!(GUARDED) || (cg2>=0 && cg2<NCH)){                                    \
        const int bg=cg2&1;                                                    \
        G2T(8, W_L2R, (&s_hh[1][bg][0][0]), (&s_hh[1][bg][1][0]),              \
            (&s_xg[bg][2][0][0]), (&s_xg[bg][2][1][0]), 0, b4,b5);             \
        G2T(8, W_L2R, (&s_hh[1][bg][2][0]), (&s_hh[1][bg][3][0]),              \
            (&s_xg[bg][2][2][0]), (&s_xg[bg][2][3][0]), 0, b4,b5);             \
    }                                                                          \
    if (!(GUARDED) || (cg3>=0 && cg3<NCH)){                                    \
        const int bg=cg3&1;                                                    \
        G1Q(8, WL3_0, (&s_hh[2][bg][0][0]), 32, (&s_xg[bg][3][0][0]),   0, b6);\
        G1Q(8, WL3_1, (&s_hh[2][bg][0][0]), 32, (&s_xg[bg][3][0][0]),  64, b7);\
        G1Q(8, WL3_2, (&s_hh[2][bg][0][0]), 32, (&s_xg[bg][3][0][0]), 128, b8);\
        G1Q(8, WL3_3, (&s_hh[2][bg][0][0]), 32, (&s_xg[bg][3][0][0]), 192, b9);\
    }                                                                          \
}while(0)

    // ================= supercycle loop =================
    for (int k=0; k<KMAX; ++k){
        if (k >= 10 && k < NCH){
            if      (wave == 0) BODY_W0(0);
            else if (wave == 1) BODY_W1(0);
            else if (wave == 2) BODY_W2(0);
            else                BODY_W3(0);
        } else {
            if      (wave == 0) BODY_W0(1);
            else if (wave == 1) BODY_W1(1);
            else if (wave == 2) BODY_W2(1);
            else                BODY_W3(1);
        }
        __syncthreads();
    }
}

// MLP head: features = gelu(last @ Wl^T + bl); out = relu(features @ Wo^T + bo)
// d_out layout: out[256*4] first, then features[256*128].
__global__ __launch_bounds__(128)
void head_kernel(const float* __restrict__ h_last,  // [256, 64]
                 const float* __restrict__ Wl,      // [128, 64]
                 const float* __restrict__ bl,      // [128]
                 const float* __restrict__ Wo,      // [4, 128]
                 const float* __restrict__ bo,      // [4]
                 float* __restrict__ d_out)
{
    __shared__ float s_last[HID];
    __shared__ float s_feat[128];
    const int s = blockIdx.x;
    const int j = threadIdx.x;

    if (j < HID) s_last[j] = h_last[(size_t)s * HID + j];
    __syncthreads();

    float acc = bl[j];
#pragma unroll
    for (int k = 0; k < HID; ++k)
        acc = fmaf(s_last[k], Wl[j * HID + k], acc);
    float f = 0.5f * acc * (1.0f + erff(acc * 0.70710678118654752440f));
    d_out[256 * 4 + s * 128 + j] = f;
    s_feat[j] = f;
    __syncthreads();

    if (j < 4) {
        float a = bo[j];
#pragma unroll
        for (int k = 0; k < 128; ++k)
            a = fmaf(s_feat[k], Wo[j * 128 + k], a);
        d_out[s * 4 + j] = fmaxf(a, 0.0f);
    }
}

extern "C" void kernel_launch(void* const* d_in, const int* in_sizes, int n_in,
                              void* d_out, int out_size, void* d_ws, size_t ws_size,
                              hipStream_t stream)
{
    const float* x         = (const float*)d_in[0];  // [256, 2048, 45]
    const float* W_ih0     = (const float*)d_in[1];  // [256, 45]
    const float* W_ih_rest = (const float*)d_in[2];  // [4, 256, 64]
    const float* W_hh      = (const float*)d_in[3];  // [5, 256, 64]
    const float* b_ih      = (const float*)d_in[4];  // [5, 256]
    const float* b_hh      = (const float*)d_in[5];  // [5, 256]
    const float* Wl        = (const float*)d_in[6];  // [128, 64]
    const float* bl        = (const float*)d_in[7];  // [128]
    const float* Wo        = (const float*)d_in[8];  // [4, 128]
    const float* bo        = (const float*)d_in[9];  // [4]

    float* h_last = (float*)d_ws;   // [256, 64] fp32

    lstm_pipe4<<<256, 256, 0, stream>>>(
        x, W_ih0, W_ih_rest, W_hh, b_ih, b_hh, h_last);
    head_kernel<<<256, 128, 0, stream>>>(h_last, Wl, bl, Wo, bo, (float*)d_out);
}

// Round 15
// 7416.052 us; speedup vs baseline: 2.3062x; 1.4039x over previous
//
#include <hip/hip_runtime.h>
#include <hip/hip_fp16.h>
#include <math.h>

#define CH    4
#define NCH   512             // 2048 timesteps / CH
#define KMAX  522             // last event: R4 chunk 511 at k = 511+10
#define HID   64
typedef unsigned int uint;
typedef __attribute__((ext_vector_type(2))) _Float16 h2t;

#define SB() __builtin_amdgcn_sched_barrier(0)

__device__ __forceinline__ float sigmoid_(float x){ return 1.0f/(1.0f+__expf(-x)); }
__device__ __forceinline__ float tanh_(float x){ float e=__expf(2.0f*x); return 1.0f-2.0f/(e+1.0f); }

__device__ __forceinline__ float fdot2_(uint w, uint h, float acc){
#if __has_builtin(__builtin_amdgcn_fdot2)
    return __builtin_amdgcn_fdot2(__builtin_bit_cast(h2t,w), __builtin_bit_cast(h2t,h), acc, false);
#else
    __half2 wv = *reinterpret_cast<const __half2*>(&w);
    __half2 hv = *reinterpret_cast<const __half2*>(&h);
    float2 wf = __half22float2(wv), hf = __half22float2(hv);
    return fmaf(wf.x, hf.x, fmaf(wf.y, hf.y, acc));
#endif
}
__device__ __forceinline__ uint packh(float a, float b){
    uint ha = (uint)__half_as_ushort(__float2half(a));   // RNE
    uint hb = (uint)__half_as_ushort(__float2half(b));
    return (hb<<16)|ha;
}
__device__ __forceinline__ uint4 pack8(const float* p){
    return make_uint4(packh(p[0],p[1]), packh(p[2],p[3]), packh(p[4],p[5]), packh(p[6],p[7]));
}

#define DOT4(A, W, H) do{ \
    A=fdot2_((W).x,(H).x,A); A=fdot2_((W).y,(H).y,A); \
    A=fdot2_((W).z,(H).z,A); A=fdot2_((W).w,(H).w,A); }while(0)

// All 5 LSTM layers, wavefront-pipelined, ONE kernel.
// grid = 256 blocks (1 sample), block = 256 threads (4 waves; VGPR cap law
// cap = 65536/block_threads -> 256).
// Round-15: CH=4 with SCHEDULER FENCES. Spill ledger: r11 (4 straight-line
// R bodies) = 252 regs OK; r13 (8 bodies, fat G2Q) = spill; r14 (2-body
// runtime loop) = spill via cross-iteration pipelining. Fix: straight-line
// R steps in groups of 4 (r11's proven envelope) separated by
// sched_barrier(0) so the scheduler cannot merge live ranges across groups;
// lean G1Q tiles (r14-validated: zero bank conflicts, weights 1x/4t).
// G-work rebalanced: w0/w1 each take one L3 G1Q from w3 (~1K fdot2/wave).
//   w0: R L0+L1 + G1Q{L4 rows 0-63, 64-127; L3 rows 128-191}
//   w1: R L2+L3 + G1Q{L4 rows 128-191, 192-255; L3 rows 192-255}
//   w2: R L4 + stage x + G4T x2 {L0, reg W} + G1Q{L2 rows 128-191, 192-255}
//   w3: G4T x2 {L1, reg W} + G2T x2 {L2 rows 0-127, reg W} + G1Q{L3 rows 0-63, 64-127}
// xg fp16 (r13/r14-validated). 522 supercycles, 1 barrier each.
// stage x(c)@k=c; G_l(c)@k=c+1+2l; R_l(c)@k=c+2+2l.
__global__ __attribute__((amdgpu_waves_per_eu(1,1))) __launch_bounds__(256)
void lstm_pipe4(const float* __restrict__ x,          // [256,2048,45]
                const float* __restrict__ W_ih0,      // [256,45]
                const float* __restrict__ W_ih_rest,  // [4,256,64]
                const float* __restrict__ W_hh,       // [5,256,64]
                const float* __restrict__ b_ih,       // [5,256]
                const float* __restrict__ b_hh,       // [5,256]
                float* __restrict__ h_last)           // [256,64] (d_ws)
{
    __shared__ __half s_xg[2][5][CH][256];      // 20480 B  xg double buffer (fp16)
    __shared__ uint  s_wo [5][8][64][4];        // 40960 B  W_hh o-gate, fp16 packed
    __shared__ uint  s_wih[10][8][64][4];       // 81920 B  W_ih groups, fp16 packed
    __shared__ uint  s_hh[4][2][CH][32];        //  4096 B  h handoff (fp16)
    __shared__ uint  s_h16[5][32];              //   640 B  per-layer running h (fp16)
    __shared__ uint  s_x[2][CH][24];            //   768 B  staged x chunk (fp16, 45+3 pad)
    // total 148864 B -> 1 block/CU

    const int tid  = threadIdx.x;
    const int wave = tid >> 6;
    const int lane = tid & 63;
    const int sm   = blockIdx.x;
    const float* x_s = x + (size_t)sm * 2048 * 45;
    float* hlast_g = h_last + (size_t)sm * HID;

    uint4 wU[48];          // per-wave weight register file (192 dwords), static-indexed
    float b0=0,b1=0,b2=0,b3=0,b4=0,b5=0,b6=0,b7=0;
    float cA=0.f, cB=0.f;  // cell states

    // ================= init: pack weights, stage LDS (r9/r11/r13-verified) =================
    if (wave == 0 || wave == 1){
#pragma unroll
        for (int li=0; li<2; ++li){
            const int L = wave*2 + li;
            const float* base = W_hh + (size_t)L*256*64;
#pragma unroll
            for (int d=0; d<8; ++d){
                wU[li*24 + 0*8 + d] = pack8(base + (size_t)(  0+lane)*64 + 8*d);  // i
                wU[li*24 + 1*8 + d] = pack8(base + (size_t)( 64+lane)*64 + 8*d);  // f
                wU[li*24 + 2*8 + d] = pack8(base + (size_t)(128+lane)*64 + 8*d);  // g
                *(uint4*)&s_wo[L][d][lane][0] = pack8(base + (size_t)(192+lane)*64 + 8*d); // o
            }
            if (lane<32) s_h16[L][lane]=0u;
        }
#pragma unroll
        for (int g=0; g<2; ++g){
            const int row = wave*128 + g*64 + lane;
            const float* src = W_ih_rest + ((size_t)3*256 + row)*64;
            const int grp = 6 + wave*2 + g;
#pragma unroll
            for (int d=0; d<8; ++d)
                *(uint4*)&s_wih[grp][d][lane][0] = pack8(src + 8*d);
        }
        { int r0 = 4*256 + wave*128 + lane, r1 = r0 + 64;
          b0 = b_ih[r0]+b_hh[r0]; b1 = b_ih[r1]+b_hh[r1]; }
        { int r2 = 3*256 + 128 + wave*64 + lane;            // L3 G1Q moved here
          b2 = b_ih[r2]+b_hh[r2]; }
    } else if (wave == 2){
        const float* base = W_hh + (size_t)4*256*64;
#pragma unroll
        for (int d=0; d<8; ++d){
            wU[0*8+d] = pack8(base + (size_t)(  0+lane)*64 + 8*d);
            wU[1*8+d] = pack8(base + (size_t)( 64+lane)*64 + 8*d);
            wU[2*8+d] = pack8(base + (size_t)(128+lane)*64 + 8*d);
            *(uint4*)&s_wo[4][d][lane][0] = pack8(base + (size_t)(192+lane)*64 + 8*d);
        }
        if (lane<32) s_h16[4][lane]=0u;
#pragma unroll
        for (int g=0; g<4; ++g){
            const float* src = W_ih0 + (size_t)(g*64+lane)*45;
#pragma unroll
            for (int d=0; d<6; ++d){
                float e0=(8*d+0<45)?src[8*d+0]:0.f, e1=(8*d+1<45)?src[8*d+1]:0.f;
                float e2=(8*d+2<45)?src[8*d+2]:0.f, e3=(8*d+3<45)?src[8*d+3]:0.f;
                float e4=(8*d+4<45)?src[8*d+4]:0.f, e5=(8*d+5<45)?src[8*d+5]:0.f;
                float e6=(8*d+6<45)?src[8*d+6]:0.f, e7=(8*d+7<45)?src[8*d+7]:0.f;
                wU[24 + g*6 + d] = make_uint4(packh(e0,e1),packh(e2,e3),packh(e4,e5),packh(e6,e7));
            }
        }
        { int r;
          r=      lane; b0=b_ih[r]+b_hh[r];
          r=  64+lane;  b1=b_ih[r]+b_hh[r];
          r= 128+lane;  b2=b_ih[r]+b_hh[r];
          r= 192+lane;  b3=b_ih[r]+b_hh[r]; }
#pragma unroll
        for (int g=0; g<2; ++g){
            const int row = 128 + g*64 + lane;
            const float* src = W_ih_rest + ((size_t)1*256 + row)*64;
#pragma unroll
            for (int d=0; d<8; ++d)
                *(uint4*)&s_wih[g][d][lane][0] = pack8(src + 8*d);
        }
        { int r0=2*256+128+lane, r1=2*256+192+lane;
          b4=b_ih[r0]+b_hh[r0]; b5=b_ih[r1]+b_hh[r1]; }
        // zero x pad halves (cols 45..47, all buf/t)
        if (lane < 2*CH*3){
            int bb=lane/(CH*3), rem=lane%(CH*3), t=rem/3, d=45+rem%3;
            ((__half*)&s_x[bb][t][0])[d]=__float2half(0.f);
        }
    } else { // wave 3
#pragma unroll
        for (int g=0; g<6; ++g){
            const int ly  = (g<4) ? 1 : 2;
            const int row = (g<4) ? g*64+lane : (g-4)*64+lane;
            const float* src = W_ih_rest + ((size_t)(ly-1)*256 + row)*64;
#pragma unroll
            for (int d=0; d<8; ++d) wU[g*8+d] = pack8(src + 8*d);
        }
        { int r;
          r=1*256+  0+lane; b0=b_ih[r]+b_hh[r];
          r=1*256+ 64+lane; b1=b_ih[r]+b_hh[r];
          r=1*256+128+lane; b2=b_ih[r]+b_hh[r];
          r=1*256+192+lane; b3=b_ih[r]+b_hh[r];
          r=2*256+  0+lane; b4=b_ih[r]+b_hh[r];
          r=2*256+ 64+lane; b5=b_ih[r]+b_hh[r];
          r=3*256+  0+lane; b6=b_ih[r]+b_hh[r];
          r=3*256+ 64+lane; b7=b_ih[r]+b_hh[r]; }
#pragma unroll
        for (int g=0; g<4; ++g){
            const float* src = W_ih_rest + ((size_t)2*256 + g*64+lane)*64;
#pragma unroll
            for (int d=0; d<8; ++d) *(uint4*)&s_wih[2+g][d][lane][0] = pack8(src + 8*d);
        }
    }
    __syncthreads();

// ---- recurrence step, no-lo, even/odd-d split chains (8 chains) ----
#define R_STEPN(L, WB, LASTF, T, C, CST) do{                                   \
    const int buf_ = (C)&1;                                                    \
    float xi_ = __half2float(s_xg[buf_][L][T][      lane]);                    \
    float xf_ = __half2float(s_xg[buf_][L][T][ 64 + lane]);                    \
    float xgg_= __half2float(s_xg[buf_][L][T][128 + lane]);                    \
    float xo_ = __half2float(s_xg[buf_][L][T][192 + lane]);                    \
    float ai0=0,ai1=0, af0=0,af1=0, ag0=0,ag1=0, ao0=0,ao1=0;                  \
    _Pragma("unroll")                                                          \
    for (int d_=0; d_<8; d_+=2){                                               \
        uint4 h0_ = *(const uint4*)&s_h16[L][4*d_];                            \
        uint4 h1_ = *(const uint4*)&s_h16[L][4*d_+4];                          \
        uint4 woA_ = *(const uint4*)&s_wo[L][d_  ][lane][0];                   \
        uint4 woB_ = *(const uint4*)&s_wo[L][d_+1][lane][0];                   \
        DOT4(ai0, wU[(WB)+d_],      h0_); DOT4(ai1, wU[(WB)+d_+1],    h1_);    \
        DOT4(af0, wU[(WB)+8+d_],    h0_); DOT4(af1, wU[(WB)+8+d_+1],  h1_);    \
        DOT4(ag0, wU[(WB)+16+d_],   h0_); DOT4(ag1, wU[(WB)+16+d_+1], h1_);    \
        DOT4(ao0, woA_,             h0_); DOT4(ao1, woB_,             h1_);    \
    }                                                                          \
    float I_=sigmoid_(xi_+(ai0+ai1)), F_=sigmoid_(xf_+(af0+af1));              \
    float G_=tanh_(xgg_+(ag0+ag1)),   O_=sigmoid_(xo_+(ao0+ao1));              \
    CST = fmaf(F_, CST, I_*G_);                                                \
    float h_ = O_*tanh_(CST);                                                  \
    __half hhi_=__float2half(h_);                                              \
    ((__half*)&s_h16[L][0])[lane]=hhi_;                                        \
    if (!(LASTF)){                                                             \
        ((__half*)&s_hh[(L)<4?(L):0][buf_][T][0])[lane]=hhi_;                  \
    } else if ((C)==NCH-1 && (T)==CH-1){ hlast_g[lane]=h_; }                   \
}while(0)

// ---- G1Q: 1 row-group x 4 timesteps, LDS weights read ONCE per chunk ----
#define G1Q(DMAX, WEXPR, HB, HSTR, XB, ROWOFF, B0_) do{                        \
    float a0=(B0_),a1=(B0_),a2=(B0_),a3=(B0_);                                 \
    _Pragma("unroll")                                                          \
    for (int d_=0; d_<(DMAX); ++d_){                                           \
        uint4 w_ = WEXPR(d_);                                                  \
        uint4 h0_=*(const uint4*)&(HB)[0*(HSTR)+4*d_];                         \
        uint4 h1_=*(const uint4*)&(HB)[1*(HSTR)+4*d_];                         \
        uint4 h2_=*(const uint4*)&(HB)[2*(HSTR)+4*d_];                         \
        uint4 h3_=*(const uint4*)&(HB)[3*(HSTR)+4*d_];                         \
        DOT4(a0,w_,h0_); DOT4(a1,w_,h1_); DOT4(a2,w_,h2_); DOT4(a3,w_,h3_);    \
    }                                                                          \
    __half* xp_ = (__half*)(XB);                                               \
    xp_[0*256+(ROWOFF)+lane]=__float2half(a0);                                 \
    xp_[1*256+(ROWOFF)+lane]=__float2half(a1);                                 \
    xp_[2*256+(ROWOFF)+lane]=__float2half(a2);                                 \
    xp_[3*256+(ROWOFF)+lane]=__float2half(a3);                                 \
}while(0)

// ---- G4T: 4 row-groups x 2 timesteps, REGISTER weights ----
#define G4T(DMAX, WEXPR, H0, H1, XD0, XD1, B0_,B1_,B2_,B3_) do{                \
    float a00=(B0_),a01=(B1_),a02=(B2_),a03=(B3_);                             \
    float a10=(B0_),a11=(B1_),a12=(B2_),a13=(B3_);                             \
    _Pragma("unroll")                                                          \
    for (int d_=0; d_<(DMAX); ++d_){                                           \
        uint4 w0_=WEXPR(0,d_), w1_=WEXPR(1,d_), w2_=WEXPR(2,d_), w3_=WEXPR(3,d_);\
        uint4 h0_=*(const uint4*)&(H0)[4*d_];                                  \
        uint4 h1_=*(const uint4*)&(H1)[4*d_];                                  \
        DOT4(a00,w0_,h0_); DOT4(a01,w1_,h0_); DOT4(a02,w2_,h0_); DOT4(a03,w3_,h0_);\
        DOT4(a10,w0_,h1_); DOT4(a11,w1_,h1_); DOT4(a12,w2_,h1_); DOT4(a13,w3_,h1_);\
    }                                                                          \
    __half* xp0_ = (__half*)(XD0);                                             \
    __half* xp1_ = (__half*)(XD1);                                             \
    xp0_[      lane]=__float2half(a00); xp0_[ 64+lane]=__float2half(a01);      \
    xp0_[128+lane]=__float2half(a02);   xp0_[192+lane]=__float2half(a03);      \
    xp1_[      lane]=__float2half(a10); xp1_[ 64+lane]=__float2half(a11);      \
    xp1_[128+lane]=__float2half(a12);   xp1_[192+lane]=__float2half(a13);      \
}while(0)

// ---- G2T: 2 row-groups x 2 timesteps, REGISTER weights ----
#define G2T(DMAX, WEXPR, H0, H1, XD0, XD1, ROWOFF, B0_,B1_) do{                \
    float a00=(B0_),a01=(B1_), a10=(B0_),a11=(B1_);                            \
    _Pragma("unroll")                                                          \
    for (int d_=0; d_<(DMAX); ++d_){                                           \
        uint4 wa_ = WEXPR(0,d_), wb_ = WEXPR(1,d_);                            \
        uint4 h0_=*(const uint4*)&(H0)[4*d_];                                  \
        uint4 h1_=*(const uint4*)&(H1)[4*d_];                                  \
        DOT4(a00,wa_,h0_); DOT4(a01,wb_,h0_);                                  \
        DOT4(a10,wa_,h1_); DOT4(a11,wb_,h1_);                                  \
    }                                                                          \
    __half* xp0_ = (__half*)(XD0);                                             \
    __half* xp1_ = (__half*)(XD1);                                             \
    xp0_[(ROWOFF)+lane]=__float2half(a00); xp0_[(ROWOFF)+64+lane]=__float2half(a01);\
    xp1_[(ROWOFF)+lane]=__float2half(a10); xp1_[(ROWOFF)+64+lane]=__float2half(a11);\
}while(0)

// weight selectors
#define W_L1(g,d)  wU[(g)*8+(d)]
#define W_L2R(g,d) wU[32+(g)*8+(d)]
#define W_L0(g,d)  wU[24+(g)*6+(d)]
#define WL2_0(d) (*(const uint4*)&s_wih[0][d][lane][0])
#define WL2_1(d) (*(const uint4*)&s_wih[1][d][lane][0])
#define WL3_0(d) (*(const uint4*)&s_wih[2][d][lane][0])
#define WL3_1(d) (*(const uint4*)&s_wih[3][d][lane][0])
#define WL3_2(d) (*(const uint4*)&s_wih[4][d][lane][0])
#define WL3_3(d) (*(const uint4*)&s_wih[5][d][lane][0])
#define WL4_0(d) (*(const uint4*)&s_wih[6][d][lane][0])
#define WL4_1(d) (*(const uint4*)&s_wih[7][d][lane][0])
#define WL4_2(d) (*(const uint4*)&s_wih[8][d][lane][0])
#define WL4_3(d) (*(const uint4*)&s_wih[9][d][lane][0])

#define STAGE_X() do{                                                          \
    const int bufx = k & 1;                                                    \
    _Pragma("unroll")                                                          \
    for (int r=0; r<3; ++r){                                                   \
        const int i = lane + 64*r;                                             \
        if (i < CH*45){                                                        \
            float v = x_s[(size_t)k*(CH*45) + i];                              \
            const int t = i/45, d = i - 45*t;                                  \
            ((__half*)&s_x[bufx][t][0])[d] = __float2half(v);                  \
        }                                                                      \
    }                                                                          \
}while(0)

// per-wave supercycle bodies (GUARDED=1 only in prologue/epilogue).
// sched_barrier(0) between groups pins register pressure to the r11-proven
// 4-R envelope and keeps each G tile's live set isolated.
#define BODY_W0(GUARDED) do{                                                   \
    const int c0=k-2, c1=k-4, cl=k-9, cg3=k-7;                                 \
    if (!(GUARDED) || (c0>=0 && c0<NCH)){ R_STEPN(0,  0, 0, 0, c0, cA); }      \
    if (!(GUARDED) || (c1>=0 && c1<NCH)){ R_STEPN(1, 24, 0, 0, c1, cB); }      \
    if (!(GUARDED) || (c0>=0 && c0<NCH)){ R_STEPN(0,  0, 0, 1, c0, cA); }      \
    if (!(GUARDED) || (c1>=0 && c1<NCH)){ R_STEPN(1, 24, 0, 1, c1, cB); }      \
    SB();                                                                      \
    if (!(GUARDED) || (c0>=0 && c0<NCH)){ R_STEPN(0,  0, 0, 2, c0, cA); }      \
    if (!(GUARDED) || (c1>=0 && c1<NCH)){ R_STEPN(1, 24, 0, 2, c1, cB); }      \
    if (!(GUARDED) || (c0>=0 && c0<NCH)){ R_STEPN(0,  0, 0, 3, c0, cA); }      \
    if (!(GUARDED) || (c1>=0 && c1<NCH)){ R_STEPN(1, 24, 0, 3, c1, cB); }      \
    SB();                                                                      \
    if (!(GUARDED) || (cl>=0 && cl<NCH)){                                      \
        const int bl=cl&1;                                                     \
        G1Q(8, WL4_0, (&s_hh[3][bl][0][0]), 32, (&s_xg[bl][4][0][0]),  0, b0); \
        G1Q(8, WL4_1, (&s_hh[3][bl][0][0]), 32, (&s_xg[bl][4][0][0]), 64, b1); \
    }                                                                          \
    SB();                                                                      \
    if (!(GUARDED) || (cg3>=0 && cg3<NCH)){                                    \
        const int bg=cg3&1;                                                    \
        G1Q(8, WL3_2, (&s_hh[2][bg][0][0]), 32, (&s_xg[bg][3][0][0]), 128, b2);\
    }                                                                          \
}while(0)

#define BODY_W1(GUARDED) do{                                                   \
    const int c2=k-6, c3=k-8, cl=k-9, cg3=k-7;                                 \
    if (!(GUARDED) || (c2>=0 && c2<NCH)){ R_STEPN(2,  0, 0, 0, c2, cA); }      \
    if (!(GUARDED) || (c3>=0 && c3<NCH)){ R_STEPN(3, 24, 0, 0, c3, cB); }      \
    if (!(GUARDED) || (c2>=0 && c2<NCH)){ R_STEPN(2,  0, 0, 1, c2, cA); }      \
    if (!(GUARDED) || (c3>=0 && c3<NCH)){ R_STEPN(3, 24, 0, 1, c3, cB); }      \
    SB();                                                                      \
    if (!(GUARDED) || (c2>=0 && c2<NCH)){ R_STEPN(2,  0, 0, 2, c2, cA); }      \
    if (!(GUARDED) || (c3>=0 && c3<NCH)){ R_STEPN(3, 24, 0, 2, c3, cB); }      \
    if (!(GUARDED) || (c2>=0 && c2<NCH)){ R_STEPN(2,  0, 0, 3, c2, cA); }      \
    if (!(GUARDED) || (c3>=0 && c3<NCH)){ R_STEPN(3, 24, 0, 3, c3, cB); }      \
    SB();                                                                      \
    if (!(GUARDED) || (cl>=0 && cl<NCH)){                                      \
        const int bl=cl&1;                                                     \
        G1Q(8, WL4_2, (&s_hh[3][bl][0][0]), 32, (&s_xg[bl][4][0][0]), 128, b0);\
        G1Q(8, WL4_3, (&s_hh[3][bl][0][0]), 32, (&s_xg[bl][4][0][0]), 192, b1);\
    }                                                                          \
    SB();                                                                      \
    if (!(GUARDED) || (cg3>=0 && cg3<NCH)){                                    \
        const int bg=cg3&1;                                                    \
        G1Q(8, WL3_3, (&s_hh[2][bg][0][0]), 32, (&s_xg[bg][3][0][0]), 192, b2);\
    }                                                                          \
}while(0)

#define BODY_W2(GUARDED) do{                                                   \
    if (!(GUARDED) || (k < NCH)) STAGE_X();                                    \
    const int c4=k-10, cg0=k-1, cg2=k-5;                                       \
    if (!(GUARDED) || (c4>=0 && c4<NCH)){ R_STEPN(4, 0, 1, 0, c4, cA); }       \
    if (!(GUARDED) || (c4>=0 && c4<NCH)){ R_STEPN(4, 0, 1, 1, c4, cA); }       \
    SB();                                                                      \
    if (!(GUARDED) || (c4>=0 && c4<NCH)){ R_STEPN(4, 0, 1, 2, c4, cA); }       \
    if (!(GUARDED) || (c4>=0 && c4<NCH)){ R_STEPN(4, 0, 1, 3, c4, cA); }       \
    SB();                                                                      \
    if (!(GUARDED) || (cg0>=0 && cg0<NCH)){                                    \
        const int bg=cg0&1;                                                    \
        G4T(6, W_L0, (&s_x[bg][0][0]), (&s_x[bg][1][0]),                       \
            (&s_xg[bg][0][0][0]), (&s_xg[bg][0][1][0]), b0,b1,b2,b3);          \
        SB();                                                                  \
        G4T(6, W_L0, (&s_x[bg][2][0]), (&s_x[bg][3][0]),                       \
            (&s_xg[bg][0][2][0]), (&s_xg[bg][0][3][0]), b0,b1,b2,b3);          \
    }                                                                          \
    SB();                                                                      \
    if (!(GUARDED) || (cg2>=0 && cg2<NCH)){                                    \
        const int bg=cg2&1;                                                    \
        G1Q(8, WL2_0, (&s_hh[1][bg][0][0]), 32, (&s_xg[bg][2][0][0]), 128, b4);\
        G1Q(8, WL2_1, (&s_hh[1][bg][0][0]), 32, (&s_xg[bg][2][0][0]), 192, b5);\
    }                                                                          \
}while(0)

#define BODY_W3(GUARDED) do{                                                   \
    const int cg1=k-3, cg2=k-5, cg3=k-7;                                       \
    if (!(GUARDED) || (cg1>=0 && cg1<NCH)){                                    \
        const int bg=cg1&1;                                                    \
        G4T(8, W_L1, (&s_hh[0][bg][0][0]), (&s_hh[0][bg][1][0]),               \
            (&s_xg[bg][1][0][0]), (&s_xg[bg][1][1][0]), b0,b1,b2,b3);          \
        SB();                                                                  \
        G4T(8, W_L1, (&s_hh[0][bg][2][0]), (&s_hh[0][bg][3][0]),               \
            (&s_xg[bg][1][2][0]), (&s_xg[bg][1][3][0]), b0,b1,b2,b3);          \
    }                                                                          \
    SB();                                                                      \
    if (!(GUARDED) || (cg2>=0 && cg2<NCH)){                                    \
        const int bg=cg2&1;                                                    \
        G2T(8, W_L2R, (&s_hh[1][bg][0][0]), (&s_hh[1][bg][1][0]),              \
            (&s_xg[bg][2][0][0]), (&s_xg[bg][2][1][0]), 0, b4,b5);             \
        G2T(8, W_L2R, (&s_hh[1][bg][2][0]), (&s_hh[1][bg][3][0]),              \
            (&s_xg[bg][2][2][0]), (&s_xg[bg][2][3][0]), 0, b4,b5);             \
    }                                                                          \
    SB();                                                                      \
    if (!(GUARDED) || (cg3>=0 && cg3<NCH)){                                    \
        const int bg=cg3&1;                                                    \
        G1Q(8, WL3_0, (&s_hh[2][bg][0][0]), 32, (&s_xg[bg][3][0][0]),   0, b6);\
        G1Q(8, WL3_1, (&s_hh[2][bg][0][0]), 32, (&s_xg[bg][3][0][0]),  64, b7);\
    }                                                                          \
}while(0)

    // ================= supercycle loop =================
    for (int k=0; k<KMAX; ++k){
        if (k >= 10 && k < NCH){
            if      (wave == 0) BODY_W0(0);
            else if (wave == 1) BODY_W1(0);
            else if (wave == 2) BODY_W2(0);
            else                BODY_W3(0);
        } else {
            if      (wave == 0) BODY_W0(1);
            else if (wave == 1) BODY_W1(1);
            else if (wave == 2) BODY_W2(1);
            else                BODY_W3(1);
        }
        __syncthreads();
    }
}

// MLP head: features = gelu(last @ Wl^T + bl); out = relu(features @ Wo^T + bo)
// d_out layout: out[256*4] first, then features[256*128].
__global__ __launch_bounds__(128)
void head_kernel(const float* __restrict__ h_last,  // [256, 64]
                 const float* __restrict__ Wl,      // [128, 64]
                 const float* __restrict__ bl,      // [128]
                 const float* __restrict__ Wo,      // [4, 128]
                 const float* __restrict__ bo,      // [4]
                 float* __restrict__ d_out)
{
    __shared__ float s_last[HID];
    __shared__ float s_feat[128];
    const int s = blockIdx.x;
    const int j = threadIdx.x;

    if (j < HID) s_last[j] = h_last[(size_t)s * HID + j];
    __syncthreads();

    float acc = bl[j];
#pragma unroll
    for (int k = 0; k < HID; ++k)
        acc = fmaf(s_last[k], Wl[j * HID + k], acc);
    float f = 0.5f * acc * (1.0f + erff(acc * 0.70710678118654752440f));
    d_out[256 * 4 + s * 128 + j] = f;
    s_feat[j] = f;
    __syncthreads();

    if (j < 4) {
        float a = bo[j];
#pragma unroll
        for (int k = 0; k < 128; ++k)
            a = fmaf(s_feat[k], Wo[j * 128 + k], a);
        d_out[s * 4 + j] = fmaxf(a, 0.0f);
    }
}

extern "C" void kernel_launch(void* const* d_in, const int* in_sizes, int n_in,
                              void* d_out, int out_size, void* d_ws, size_t ws_size,
                              hipStream_t stream)
{
    const float* x         = (const float*)d_in[0];  // [256, 2048, 45]
    const float* W_ih0     = (const float*)d_in[1];  // [256, 45]
    const float* W_ih_rest = (const float*)d_in[2];  // [4, 256, 64]
    const float* W_hh      = (const float*)d_in[3];  // [5, 256, 64]
    const float* b_ih      = (const float*)d_in[4];  // [5, 256]
    const float* b_hh      = (const float*)d_in[5];  // [5, 256]
    const float* Wl        = (const float*)d_in[6];  // [128, 64]
    const float* bl        = (const float*)d_in[7];  // [128]
    const float* Wo        = (const float*)d_in[8];  // [4, 128]
    const float* bo        = (const float*)d_in[9];  // [4]

    float* h_last = (float*)d_ws;   // [256, 64] fp32

    lstm_pipe4<<<256, 256, 0, stream>>>(
        x, W_ih0, W_ih_rest, W_hh, b_ih, b_hh, h_last);
    head_kernel<<<256, 128, 0, stream>>>(h_last, Wl, bl, Wo, bo, (float*)d_out);
}

// Round 16
// 5554.461 us; speedup vs baseline: 3.0791x; 1.3352x over previous
//
#include <hip/hip_runtime.h>
#include <hip/hip_fp16.h>
#include <math.h>

#define NCH   1024            // 2048 timesteps / CH=2
#define KMAX  1034            // last event: R4 chunk 1023 at k = 1023+10
#define HID   64
typedef unsigned int uint;
typedef __attribute__((ext_vector_type(2))) _Float16 h2t;

__device__ __forceinline__ float sigmoid_(float x){ return 1.0f/(1.0f+__expf(-x)); }
__device__ __forceinline__ float tanh_(float x){ float e=__expf(2.0f*x); return 1.0f-2.0f/(e+1.0f); }

__device__ __forceinline__ float fdot2_(uint w, uint h, float acc){
#if __has_builtin(__builtin_amdgcn_fdot2)
    return __builtin_amdgcn_fdot2(__builtin_bit_cast(h2t,w), __builtin_bit_cast(h2t,h), acc, false);
#else
    __half2 wv = *reinterpret_cast<const __half2*>(&w);
    __half2 hv = *reinterpret_cast<const __half2*>(&h);
    float2 wf = __half22float2(wv), hf = __half22float2(hv);
    return fmaf(wf.x, hf.x, fmaf(wf.y, hf.y, acc));
#endif
}
__device__ __forceinline__ uint packh(float a, float b){
    uint ha = (uint)__half_as_ushort(__float2half(a));   // RNE
    uint hb = (uint)__half_as_ushort(__float2half(b));
    return (hb<<16)|ha;
}
__device__ __forceinline__ uint4 pack8(const float* p){
    return make_uint4(packh(p[0],p[1]), packh(p[2],p[3]), packh(p[4],p[5]), packh(p[6],p[7]));
}

#define DOT4(A, W, H) do{ \
    A=fdot2_((W).x,(H).x,A); A=fdot2_((W).y,(H).y,A); \
    A=fdot2_((W).z,(H).z,A); A=fdot2_((W).w,(H).w,A); }while(0)

// All 5 LSTM layers, wavefront-pipelined, ONE kernel.
// grid = 256 blocks (1 sample), block = 256 threads (4 waves; VGPR cap law
// cap = 65536/block_threads -> 256; r11 proved this exact structure = 252,
// no spill; r13/r14/r15 proved CH=4 always spills -> CH=2 is final).
// Round-16 = EXACT r11 + transposed fp16 xg: s_xgT[buf][L][t][unit][4 gates]
// so each R step reads all 4 gate pre-activations with ONE ds_read_b64
// (was 4 stride-256 reads) and G4T writes ONE ds_write_b64 (was 4 stores).
// fp16 xg validated r13/r14/r15 (absmax pinned at 1.2207e-4).
//   w0: R L0+L1 + xg[L4] gates 0,1 (LDS W)
//   w1: R L2+L3 + xg[L4] gates 2,3 (LDS W)
//   w2: R L4 + stage x + xg[L0] (reg W) + xg[L2] gates 2,3 (LDS W)
//   w3: xg[L1] (reg W) + xg[L2] gates 0,1 (reg W) + xg[L3] (LDS W)
// 1034 supercycles, one __syncthreads each.
// stage x(c)@k=c; G_l(c)@k=c+1+2l; R_l(c)@k=c+2+2l.
__global__ __attribute__((amdgpu_waves_per_eu(1,1))) __launch_bounds__(256)
void lstm_pipe4(const float* __restrict__ x,          // [256,2048,45]
                const float* __restrict__ W_ih0,      // [256,45]
                const float* __restrict__ W_ih_rest,  // [4,256,64]
                const float* __restrict__ W_hh,       // [5,256,64]
                const float* __restrict__ b_ih,       // [5,256]
                const float* __restrict__ b_hh,       // [5,256]
                float* __restrict__ h_last)           // [256,64] (d_ws)
{
    __shared__ uint2 s_xgT[2][5][2][64];        // 10240 B  xg: [buf][L][t][unit]{i,f | g,o} fp16
    __shared__ uint  s_wo [5][8][64][4];        // 40960 B  W_hh o-gate, fp16 packed
    __shared__ uint  s_wih[10][8][64][4];       // 81920 B  W_ih groups, fp16 packed
    __shared__ uint  s_hh[4][2][2][32];         //  2048 B  h handoff (fp16)
    __shared__ uint  s_h16[5][32];              //   640 B  per-layer running h (fp16)
    __shared__ uint  s_x[2][2][24];             //   384 B  staged x chunk (fp16, 45+3 pad)
    // total 136192 B -> 1 block/CU

    const int tid  = threadIdx.x;
    const int wave = tid >> 6;
    const int lane = tid & 63;
    const int sm   = blockIdx.x;
    const float* x_s = x + (size_t)sm * 2048 * 45;
    float* hlast_g = h_last + (size_t)sm * HID;

    uint4 wU[48];          // per-wave weight register file (192 dwords), static-indexed
    float b0=0,b1=0,b2=0,b3=0,b4=0,b5=0,b6=0,b7=0,b8=0,b9=0;
    float cA=0.f, cB=0.f;  // cell states

    // ================= init: pack weights, stage LDS (r9/r11-verified) =================
    if (wave == 0 || wave == 1){
#pragma unroll
        for (int li=0; li<2; ++li){
            const int L = wave*2 + li;
            const float* base = W_hh + (size_t)L*256*64;
#pragma unroll
            for (int d=0; d<8; ++d){
                wU[li*24 + 0*8 + d] = pack8(base + (size_t)(  0+lane)*64 + 8*d);  // i
                wU[li*24 + 1*8 + d] = pack8(base + (size_t)( 64+lane)*64 + 8*d);  // f
                wU[li*24 + 2*8 + d] = pack8(base + (size_t)(128+lane)*64 + 8*d);  // g
                *(uint4*)&s_wo[L][d][lane][0] = pack8(base + (size_t)(192+lane)*64 + 8*d); // o
            }
            if (lane<32) s_h16[L][lane]=0u;
        }
#pragma unroll
        for (int g=0; g<2; ++g){
            const int row = wave*128 + g*64 + lane;
            const float* src = W_ih_rest + ((size_t)3*256 + row)*64;
            const int grp = 6 + wave*2 + g;
#pragma unroll
            for (int d=0; d<8; ++d)
                *(uint4*)&s_wih[grp][d][lane][0] = pack8(src + 8*d);
        }
        { int r0 = 4*256 + wave*128 + lane, r1 = r0 + 64;
          b0 = b_ih[r0]+b_hh[r0]; b1 = b_ih[r1]+b_hh[r1]; }
    } else if (wave == 2){
        const float* base = W_hh + (size_t)4*256*64;
#pragma unroll
        for (int d=0; d<8; ++d){
            wU[0*8+d] = pack8(base + (size_t)(  0+lane)*64 + 8*d);
            wU[1*8+d] = pack8(base + (size_t)( 64+lane)*64 + 8*d);
            wU[2*8+d] = pack8(base + (size_t)(128+lane)*64 + 8*d);
            *(uint4*)&s_wo[4][d][lane][0] = pack8(base + (size_t)(192+lane)*64 + 8*d);
        }
        if (lane<32) s_h16[4][lane]=0u;
#pragma unroll
        for (int g=0; g<4; ++g){
            const float* src = W_ih0 + (size_t)(g*64+lane)*45;
#pragma unroll
            for (int d=0; d<6; ++d){
                float e0=(8*d+0<45)?src[8*d+0]:0.f, e1=(8*d+1<45)?src[8*d+1]:0.f;
                float e2=(8*d+2<45)?src[8*d+2]:0.f, e3=(8*d+3<45)?src[8*d+3]:0.f;
                float e4=(8*d+4<45)?src[8*d+4]:0.f, e5=(8*d+5<45)?src[8*d+5]:0.f;
                float e6=(8*d+6<45)?src[8*d+6]:0.f, e7=(8*d+7<45)?src[8*d+7]:0.f;
                wU[24 + g*6 + d] = make_uint4(packh(e0,e1),packh(e2,e3),packh(e4,e5),packh(e6,e7));
            }
        }
        { int r;
          r=      lane; b0=b_ih[r]+b_hh[r];
          r=  64+lane;  b1=b_ih[r]+b_hh[r];
          r= 128+lane;  b2=b_ih[r]+b_hh[r];
          r= 192+lane;  b3=b_ih[r]+b_hh[r]; }
#pragma unroll
        for (int g=0; g<2; ++g){
            const int row = 128 + g*64 + lane;
            const float* src = W_ih_rest + ((size_t)1*256 + row)*64;
#pragma unroll
            for (int d=0; d<8; ++d)
                *(uint4*)&s_wih[g][d][lane][0] = pack8(src + 8*d);
        }
        { int r0=2*256+128+lane, r1=2*256+192+lane;
          b4=b_ih[r0]+b_hh[r0]; b5=b_ih[r1]+b_hh[r1]; }
        if (lane < 12){
            int bb=lane/6, t=(lane%6)/3, d=45+lane%3;
            ((__half*)&s_x[bb][t][0])[d]=__float2half(0.f);
        }
    } else { // wave 3
#pragma unroll
        for (int g=0; g<6; ++g){
            const int ly  = (g<4) ? 1 : 2;
            const int row = (g<4) ? g*64+lane : (g-4)*64+lane;
            const float* src = W_ih_rest + ((size_t)(ly-1)*256 + row)*64;
#pragma unroll
            for (int d=0; d<8; ++d) wU[g*8+d] = pack8(src + 8*d);
        }
        { int r;
          r=1*256+  0+lane; b0=b_ih[r]+b_hh[r];
          r=1*256+ 64+lane; b1=b_ih[r]+b_hh[r];
          r=1*256+128+lane; b2=b_ih[r]+b_hh[r];
          r=1*256+192+lane; b3=b_ih[r]+b_hh[r];
          r=2*256+  0+lane; b4=b_ih[r]+b_hh[r];
          r=2*256+ 64+lane; b5=b_ih[r]+b_hh[r]; }
#pragma unroll
        for (int g=0; g<4; ++g){
            const float* src = W_ih_rest + ((size_t)2*256 + g*64+lane)*64;
#pragma unroll
            for (int d=0; d<8; ++d) *(uint4*)&s_wih[2+g][d][lane][0] = pack8(src + 8*d);
        }
        { int r;
          r=3*256+  0+lane; b6=b_ih[r]+b_hh[r];
          r=3*256+ 64+lane; b7=b_ih[r]+b_hh[r];
          r=3*256+128+lane; b8=b_ih[r]+b_hh[r];
          r=3*256+192+lane; b9=b_ih[r]+b_hh[r]; }
    }
    __syncthreads();

// ---- recurrence step: ONE ds_read_b64 gets all 4 gate pre-activations ----
#define R_STEPN(L, WB, LASTF, T, C, CST) do{                                   \
    const int buf_ = (C)&1;                                                    \
    uint2 xg2_ = s_xgT[buf_][L][T][lane];                                      \
    float2 x01_ = __half22float2(*reinterpret_cast<__half2*>(&xg2_.x));        \
    float2 x23_ = __half22float2(*reinterpret_cast<__half2*>(&xg2_.y));        \
    float ai0=0,ai1=0, af0=0,af1=0, ag0=0,ag1=0, ao0=0,ao1=0;                  \
    _Pragma("unroll")                                                          \
    for (int d_=0; d_<8; d_+=2){                                               \
        uint4 h0_ = *(const uint4*)&s_h16[L][4*d_];                            \
        uint4 h1_ = *(const uint4*)&s_h16[L][4*d_+4];                          \
        uint4 woA_ = *(const uint4*)&s_wo[L][d_  ][lane][0];                   \
        uint4 woB_ = *(const uint4*)&s_wo[L][d_+1][lane][0];                   \
        DOT4(ai0, wU[(WB)+d_],      h0_); DOT4(ai1, wU[(WB)+d_+1],    h1_);    \
        DOT4(af0, wU[(WB)+8+d_],    h0_); DOT4(af1, wU[(WB)+8+d_+1],  h1_);    \
        DOT4(ag0, wU[(WB)+16+d_],   h0_); DOT4(ag1, wU[(WB)+16+d_+1], h1_);    \
        DOT4(ao0, woA_,             h0_); DOT4(ao1, woB_,             h1_);    \
    }                                                                          \
    float I_=sigmoid_(x01_.x+(ai0+ai1)), F_=sigmoid_(x01_.y+(af0+af1));        \
    float G_=tanh_(x23_.x+(ag0+ag1)),    O_=sigmoid_(x23_.y+(ao0+ao1));        \
    CST = fmaf(F_, CST, I_*G_);                                                \
    float h_ = O_*tanh_(CST);                                                  \
    __half hhi_=__float2half(h_);                                              \
    ((__half*)&s_h16[L][0])[lane]=hhi_;                                        \
    if (!(LASTF)){                                                             \
        ((__half*)&s_hh[(L)<4?(L):0][buf_][T][0])[lane]=hhi_;                  \
    } else if ((C)==NCH-1 && (T)==1){ hlast_g[lane]=h_; }                      \
}while(0)

// ---- G4T: all 4 gates of unit `lane` x 2 timesteps -> ONE b64 write per t ----
// XT0/XT1: uint2* = &s_xgT[buf][ly][t][0]
#define G4T(DMAX, WEXPR, H0, H1, XT0, XT1, B0_,B1_,B2_,B3_) do{                \
    float a00=(B0_),a01=(B1_),a02=(B2_),a03=(B3_);                             \
    float a10=(B0_),a11=(B1_),a12=(B2_),a13=(B3_);                             \
    _Pragma("unroll")                                                          \
    for (int d_=0; d_<(DMAX); ++d_){                                           \
        uint4 w0_=WEXPR(0,d_), w1_=WEXPR(1,d_), w2_=WEXPR(2,d_), w3_=WEXPR(3,d_);\
        uint4 h0_=*(const uint4*)&(H0)[4*d_];                                  \
        uint4 h1_=*(const uint4*)&(H1)[4*d_];                                  \
        DOT4(a00,w0_,h0_); DOT4(a01,w1_,h0_); DOT4(a02,w2_,h0_); DOT4(a03,w3_,h0_);\
        DOT4(a10,w0_,h1_); DOT4(a11,w1_,h1_); DOT4(a12,w2_,h1_); DOT4(a13,w3_,h1_);\
    }                                                                          \
    (XT0)[lane] = make_uint2(packh(a00,a01), packh(a02,a03));                  \
    (XT1)[lane] = make_uint2(packh(a10,a11), packh(a12,a13));                  \
}while(0)

// ---- G2T: gate pair (G0IDX*2, G0IDX*2+1) of unit `lane` -> ONE b32 write per t ----
#define G2T(DMAX, WEXPR, H0, H1, XT0, XT1, G0IDX, B0_,B1_) do{                 \
    float a00=(B0_),a01=(B1_), a10=(B0_),a11=(B1_);                            \
    _Pragma("unroll")                                                          \
    for (int d_=0; d_<(DMAX); ++d_){                                           \
        uint4 wa_ = WEXPR(0,d_), wb_ = WEXPR(1,d_);                            \
        uint4 h0_=*(const uint4*)&(H0)[4*d_];                                  \
        uint4 h1_=*(const uint4*)&(H1)[4*d_];                                  \
        DOT4(a00,wa_,h0_); DOT4(a01,wb_,h0_);                                  \
        DOT4(a10,wa_,h1_); DOT4(a11,wb_,h1_);                                  \
    }                                                                          \
    ((uint*)&(XT0)[lane])[G0IDX] = packh(a00,a01);                             \
    ((uint*)&(XT1)[lane])[G0IDX] = packh(a10,a11);                             \
}while(0)

// weight selectors
#define W_L1(g,d)  wU[(g)*8+(d)]
#define W_L2R(g,d) wU[32+(g)*8+(d)]
#define W_L0(g,d)  wU[24+(g)*6+(d)]
#define W_L2L(g,d) (*(const uint4*)&s_wih[(g)][d][lane][0])
#define W_L3(g,d)  (*(const uint4*)&s_wih[2+(g)][d][lane][0])
#define W_L4A(g,d) (*(const uint4*)&s_wih[6+(g)][d][lane][0])
#define W_L4B(g,d) (*(const uint4*)&s_wih[8+(g)][d][lane][0])

#define STAGE_X() do{                                                          \
    const int bufx = k & 1;                                                    \
    _Pragma("unroll")                                                          \
    for (int r=0; r<2; ++r){                                                   \
        const int i = lane + 64*r;                                             \
        if (i < 90){                                                           \
            float v = x_s[(size_t)k*90 + i];                                   \
            const int t = i/45, d = i - 45*t;                                  \
            ((__half*)&s_x[bufx][t][0])[d] = __float2half(v);                  \
        }                                                                      \
    }                                                                          \
}while(0)

// per-wave supercycle bodies (shared by fast/slow path; guards only in slow)
#define BODY_W0(GUARDED) do{                                                   \
    const int c0=k-2, c1=k-4, cl=k-9;                                          \
    if (!(GUARDED) || (c0>=0 && c0<NCH)){ R_STEPN(0,  0, 0, 0, c0, cA); }      \
    if (!(GUARDED) || (c1>=0 && c1<NCH)){ R_STEPN(1, 24, 0, 0, c1, cB); }      \
    if (!(GUARDED) || (c0>=0 && c0<NCH)){ R_STEPN(0,  0, 0, 1, c0, cA); }      \
    if (!(GUARDED) || (c1>=0 && c1<NCH)){ R_STEPN(1, 24, 0, 1, c1, cB); }      \
    if (!(GUARDED) || (cl>=0 && cl<NCH)){                                      \
        const int bl=cl&1;                                                     \
        G2T(8, W_L4A, (&s_hh[3][bl][0][0]), (&s_hh[3][bl][1][0]),              \
            (&s_xgT[bl][4][0][0]), (&s_xgT[bl][4][1][0]), 0, b0,b1); }         \
}while(0)

#define BODY_W1(GUARDED) do{                                                   \
    const int c2=k-6, c3=k-8, cl=k-9;                                          \
    if (!(GUARDED) || (c2>=0 && c2<NCH)){ R_STEPN(2,  0, 0, 0, c2, cA); }      \
    if (!(GUARDED) || (c3>=0 && c3<NCH)){ R_STEPN(3, 24, 0, 0, c3, cB); }      \
    if (!(GUARDED) || (c2>=0 && c2<NCH)){ R_STEPN(2,  0, 0, 1, c2, cA); }      \
    if (!(GUARDED) || (c3>=0 && c3<NCH)){ R_STEPN(3, 24, 0, 1, c3, cB); }      \
    if (!(GUARDED) || (cl>=0 && cl<NCH)){                                      \
        const int bl=cl&1;                                                     \
        G2T(8, W_L4B, (&s_hh[3][bl][0][0]), (&s_hh[3][bl][1][0]),              \
            (&s_xgT[bl][4][0][0]), (&s_xgT[bl][4][1][0]), 1, b0,b1); }         \
}while(0)

#define BODY_W2(GUARDED) do{                                                   \
    if (!(GUARDED) || (k < NCH)) STAGE_X();                                    \
    const int c4=k-10, cg0=k-1, cg2=k-5;                                       \
    if (!(GUARDED) || (c4>=0 && c4<NCH)){ R_STEPN(4, 0, 1, 0, c4, cA); }       \
    if (!(GUARDED) || (cg0>=0 && cg0<NCH)){                                    \
        const int bg=cg0&1;                                                    \
        G4T(6, W_L0, (&s_x[bg][0][0]), (&s_x[bg][1][0]),                       \
            (&s_xgT[bg][0][0][0]), (&s_xgT[bg][0][1][0]), b0,b1,b2,b3); }      \
    if (!(GUARDED) || (c4>=0 && c4<NCH)){ R_STEPN(4, 0, 1, 1, c4, cA); }       \
    if (!(GUARDED) || (cg2>=0 && cg2<NCH)){                                    \
        const int bg=cg2&1;                                                    \
        G2T(8, W_L2L, (&s_hh[1][bg][0][0]), (&s_hh[1][bg][1][0]),              \
            (&s_xgT[bg][2][0][0]), (&s_xgT[bg][2][1][0]), 1, b4,b5); }         \
}while(0)

#define BODY_W3(GUARDED) do{                                                   \
    const int cg1=k-3, cg2=k-5, cg3=k-7;                                       \
    if (!(GUARDED) || (cg1>=0 && cg1<NCH)){                                    \
        const int bg=cg1&1;                                                    \
        G4T(8, W_L1, (&s_hh[0][bg][0][0]), (&s_hh[0][bg][1][0]),               \
            (&s_xgT[bg][1][0][0]), (&s_xgT[bg][1][1][0]), b0,b1,b2,b3); }      \
    if (!(GUARDED) || (cg2>=0 && cg2<NCH)){                                    \
        const int bg=cg2&1;                                                    \
        G2T(8, W_L2R, (&s_hh[1][bg][0][0]), (&s_hh[1][bg][1][0]),              \
            (&s_xgT[bg][2][0][0]), (&s_xgT[bg][2][1][0]), 0, b4,b5); }         \
    if (!(GUARDED) || (cg3>=0 && cg3<NCH)){                                    \
        const int bg=cg3&1;                                                    \
        G4T(8, W_L3, (&s_hh[2][bg][0][0]), (&s_hh[2][bg][1][0]),               \
            (&s_xgT[bg][3][0][0]), (&s_xgT[bg][3][1][0]), b6,b7,b8,b9); }      \
}while(0)

    // ================= supercycle loop =================
    for (int k=0; k<KMAX; ++k){
        if (k >= 10 && k < NCH){
            // ---------- FAST PATH: all pieces valid, no guards ----------
            if      (wave == 0) BODY_W0(0);
            else if (wave == 1) BODY_W1(0);
            else if (wave == 2) BODY_W2(0);
            else                BODY_W3(0);
        } else {
            // ---------- SLOW PATH: prologue/epilogue, guarded ----------
            if      (wave == 0) BODY_W0(1);
            else if (wave == 1) BODY_W1(1);
            else if (wave == 2) BODY_W2(1);
            else                BODY_W3(1);
        }
        __syncthreads();
    }
}

// MLP head: features = gelu(last @ Wl^T + bl); out = relu(features @ Wo^T + bo)
// d_out layout: out[256*4] first, then features[256*128].
__global__ __launch_bounds__(128)
void head_kernel(const float* __restrict__ h_last,  // [256, 64]
                 const float* __restrict__ Wl,      // [128, 64]
                 const float* __restrict__ bl,      // [128]
                 const float* __restrict__ Wo,      // [4, 128]
                 const float* __restrict__ bo,      // [4]
                 float* __restrict__ d_out)
{
    __shared__ float s_last[HID];
    __shared__ float s_feat[128];
    const int s = blockIdx.x;
    const int j = threadIdx.x;

    if (j < HID) s_last[j] = h_last[(size_t)s * HID + j];
    __syncthreads();

    float acc = bl[j];
#pragma unroll
    for (int k = 0; k < HID; ++k)
        acc = fmaf(s_last[k], Wl[j * HID + k], acc);
    float f = 0.5f * acc * (1.0f + erff(acc * 0.70710678118654752440f));
    d_out[256 * 4 + s * 128 + j] = f;
    s_feat[j] = f;
    __syncthreads();

    if (j < 4) {
        float a = bo[j];
#pragma unroll
        for (int k = 0; k < 128; ++k)
            a = fmaf(s_feat[k], Wo[j * 128 + k], a);
        d_out[s * 4 + j] = fmaxf(a, 0.0f);
    }
}

extern "C" void kernel_launch(void* const* d_in, const int* in_sizes, int n_in,
                              void* d_out, int out_size, void* d_ws, size_t ws_size,
                              hipStream_t stream)
{
    const float* x         = (const float*)d_in[0];  // [256, 2048, 45]
    const float* W_ih0     = (const float*)d_in[1];  // [256, 45]
    const float* W_ih_rest = (const float*)d_in[2];  // [4, 256, 64]
    const float* W_hh      = (const float*)d_in[3];  // [5, 256, 64]
    const float* b_ih      = (const float*)d_in[4];  // [5, 256]
    const float* b_hh      = (const float*)d_in[5];  // [5, 256]
    const float* Wl        = (const float*)d_in[6];  // [128, 64]
    const float* bl        = (const float*)d_in[7];  // [128]
    const float* Wo        = (const float*)d_in[8];  // [4, 128]
    const float* bo        = (const float*)d_in[9];  // [4]

    float* h_last = (float*)d_ws;   // [256, 64] fp32

    lstm_pipe4<<<256, 256, 0, stream>>>(
        x, W_ih0, W_ih_rest, W_hh, b_ih, b_hh, h_last);
    head_kernel<<<256, 128, 0, stream>>>(h_last, Wl, bl, Wo, bo, (float*)d_out);
}

// Round 17
// 4621.819 us; speedup vs baseline: 3.7005x; 1.2018x over previous
//
#include <hip/hip_runtime.h>
#include <hip/hip_fp16.h>
#include <math.h>

#define NCH   1024            // 2048 timesteps / CH=2
#define KMAX  1034            // last event: R4 chunk 1023 at k = 1023+10
#define HID   64
typedef unsigned int uint;
typedef __attribute__((ext_vector_type(2))) _Float16 h2t;

__device__ __forceinline__ float sigmoid_(float x){ return 1.0f/(1.0f+__expf(-x)); }
__device__ __forceinline__ float tanh_(float x){ float e=__expf(2.0f*x); return 1.0f-2.0f/(e+1.0f); }

__device__ __forceinline__ float fdot2_(uint w, uint h, float acc){
#if __has_builtin(__builtin_amdgcn_fdot2)
    return __builtin_amdgcn_fdot2(__builtin_bit_cast(h2t,w), __builtin_bit_cast(h2t,h), acc, false);
#else
    __half2 wv = *reinterpret_cast<const __half2*>(&w);
    __half2 hv = *reinterpret_cast<const __half2*>(&h);
    float2 wf = __half22float2(wv), hf = __half22float2(hv);
    return fmaf(wf.x, hf.x, fmaf(wf.y, hf.y, acc));
#endif
}
__device__ __forceinline__ uint packh(float a, float b){
    uint ha = (uint)__half_as_ushort(__float2half(a));   // RNE
    uint hb = (uint)__half_as_ushort(__float2half(b));
    return (hb<<16)|ha;
}
__device__ __forceinline__ uint4 pack8(const float* p){
    return make_uint4(packh(p[0],p[1]), packh(p[2],p[3]), packh(p[4],p[5]), packh(p[6],p[7]));
}

#define DOT4(A, W, H) do{ \
    A=fdot2_((W).x,(H).x,A); A=fdot2_((W).y,(H).y,A); \
    A=fdot2_((W).z,(H).z,A); A=fdot2_((W).w,(H).w,A); }while(0)

// All 5 LSTM layers, wavefront-pipelined, ONE kernel. (EXACT r11 revert —
// measured optimum: 4.62 ms total, VGPR 252, no spill.)
// grid = 256 blocks (1 sample), block = 256 threads (4 waves; VGPR cap law
// cap = 65536/block_threads -> 256; this structure = 252, no spill).
// CH=2 steps/chunk, 1034 supercycles, one __syncthreads each.
//   w0: recurrence L0+L1 + xg[L4] rows 0-127 (LDS W)
//   w1: recurrence L2+L3 + xg[L4] rows 128-255 (LDS W)
//   w2: recurrence L4 + stage x + xg[L0] (reg W, K=45) + xg[L2] rows 128-255 (LDS W)
//   w3: xg[L1] (reg W) + xg[L2] rows 0-127 (reg W) + xg[L3] (LDS W)
// h stored plain fp16 (validated: absmax 1.2207e-4, dominated by fp16 weight
// rounding). G blocks d-outer/t-inner (weights read once per supercycle).
// Fast path without guards for k in [10, NCH).
// Schedule: stage x(c)@k=c; G_l(c)@k=c+1+2l; R_l(c)@k=c+2+2l.
__global__ __attribute__((amdgpu_waves_per_eu(1,1))) __launch_bounds__(256)
void lstm_pipe4(const float* __restrict__ x,          // [256,2048,45]
                const float* __restrict__ W_ih0,      // [256,45]
                const float* __restrict__ W_ih_rest,  // [4,256,64]
                const float* __restrict__ W_hh,       // [5,256,64]
                const float* __restrict__ b_ih,       // [5,256]
                const float* __restrict__ b_hh,       // [5,256]
                float* __restrict__ h_last)           // [256,64] (d_ws)
{
    __shared__ float s_xg[2][5][2][256];        // 20480 B  xg double buffer (fp32)
    __shared__ uint  s_wo [5][8][64][4];        // 40960 B  W_hh o-gate, fp16 packed
    __shared__ uint  s_wih[10][8][64][4];       // 81920 B  W_ih groups, fp16 packed
    __shared__ uint  s_hh[4][2][2][32];         //  2048 B  h handoff (fp16)
    __shared__ uint  s_h16[5][32];              //   640 B  per-layer running h (fp16)
    __shared__ uint  s_x[2][2][24];             //   384 B  staged x chunk (fp16, 45+3 pad)
    // total 146432 B -> 1 block/CU

    const int tid  = threadIdx.x;
    const int wave = tid >> 6;
    const int lane = tid & 63;
    const int sm   = blockIdx.x;
    const float* x_s = x + (size_t)sm * 2048 * 45;
    float* hlast_g = h_last + (size_t)sm * HID;

    uint4 wU[48];          // per-wave weight register file (192 dwords), static-indexed
    float b0=0,b1=0,b2=0,b3=0,b4=0,b5=0,b6=0,b7=0,b8=0,b9=0;
    float cA=0.f, cB=0.f;  // cell states

    // ================= init: pack weights, stage LDS (r9-verified) =================
    if (wave == 0 || wave == 1){
#pragma unroll
        for (int li=0; li<2; ++li){
            const int L = wave*2 + li;
            const float* base = W_hh + (size_t)L*256*64;
#pragma unroll
            for (int d=0; d<8; ++d){
                wU[li*24 + 0*8 + d] = pack8(base + (size_t)(  0+lane)*64 + 8*d);  // i
                wU[li*24 + 1*8 + d] = pack8(base + (size_t)( 64+lane)*64 + 8*d);  // f
                wU[li*24 + 2*8 + d] = pack8(base + (size_t)(128+lane)*64 + 8*d);  // g
                *(uint4*)&s_wo[L][d][lane][0] = pack8(base + (size_t)(192+lane)*64 + 8*d); // o
            }
            if (lane<32) s_h16[L][lane]=0u;
        }
#pragma unroll
        for (int g=0; g<2; ++g){
            const int row = wave*128 + g*64 + lane;
            const float* src = W_ih_rest + ((size_t)3*256 + row)*64;
            const int grp = 6 + wave*2 + g;
#pragma unroll
            for (int d=0; d<8; ++d)
                *(uint4*)&s_wih[grp][d][lane][0] = pack8(src + 8*d);
        }
        { int r0 = 4*256 + wave*128 + lane, r1 = r0 + 64;
          b0 = b_ih[r0]+b_hh[r0]; b1 = b_ih[r1]+b_hh[r1]; }
    } else if (wave == 2){
        const float* base = W_hh + (size_t)4*256*64;
#pragma unroll
        for (int d=0; d<8; ++d){
            wU[0*8+d] = pack8(base + (size_t)(  0+lane)*64 + 8*d);
            wU[1*8+d] = pack8(base + (size_t)( 64+lane)*64 + 8*d);
            wU[2*8+d] = pack8(base + (size_t)(128+lane)*64 + 8*d);
            *(uint4*)&s_wo[4][d][lane][0] = pack8(base + (size_t)(192+lane)*64 + 8*d);
        }
        if (lane<32) s_h16[4][lane]=0u;
#pragma unroll
        for (int g=0; g<4; ++g){
            const float* src = W_ih0 + (size_t)(g*64+lane)*45;
#pragma unroll
            for (int d=0; d<6; ++d){
                float e0=(8*d+0<45)?src[8*d+0]:0.f, e1=(8*d+1<45)?src[8*d+1]:0.f;
                float e2=(8*d+2<45)?src[8*d+2]:0.f, e3=(8*d+3<45)?src[8*d+3]:0.f;
                float e4=(8*d+4<45)?src[8*d+4]:0.f, e5=(8*d+5<45)?src[8*d+5]:0.f;
                float e6=(8*d+6<45)?src[8*d+6]:0.f, e7=(8*d+7<45)?src[8*d+7]:0.f;
                wU[24 + g*6 + d] = make_uint4(packh(e0,e1),packh(e2,e3),packh(e4,e5),packh(e6,e7));
            }
        }
        { int r;
          r=      lane; b0=b_ih[r]+b_hh[r];
          r=  64+lane;  b1=b_ih[r]+b_hh[r];
          r= 128+lane;  b2=b_ih[r]+b_hh[r];
          r= 192+lane;  b3=b_ih[r]+b_hh[r]; }
#pragma unroll
        for (int g=0; g<2; ++g){
            const int row = 128 + g*64 + lane;
            const float* src = W_ih_rest + ((size_t)1*256 + row)*64;
#pragma unroll
            for (int d=0; d<8; ++d)
                *(uint4*)&s_wih[g][d][lane][0] = pack8(src + 8*d);
        }
        { int r0=2*256+128+lane, r1=2*256+192+lane;
          b4=b_ih[r0]+b_hh[r0]; b5=b_ih[r1]+b_hh[r1]; }
        if (lane < 12){
            int bb=lane/6, t=(lane%6)/3, d=45+lane%3;
            ((__half*)&s_x[bb][t][0])[d]=__float2half(0.f);
        }
    } else { // wave 3
#pragma unroll
        for (int g=0; g<6; ++g){
            const int ly  = (g<4) ? 1 : 2;
            const int row = (g<4) ? g*64+lane : (g-4)*64+lane;
            const float* src = W_ih_rest + ((size_t)(ly-1)*256 + row)*64;
#pragma unroll
            for (int d=0; d<8; ++d) wU[g*8+d] = pack8(src + 8*d);
        }
        { int r;
          r=1*256+  0+lane; b0=b_ih[r]+b_hh[r];
          r=1*256+ 64+lane; b1=b_ih[r]+b_hh[r];
          r=1*256+128+lane; b2=b_ih[r]+b_hh[r];
          r=1*256+192+lane; b3=b_ih[r]+b_hh[r];
          r=2*256+  0+lane; b4=b_ih[r]+b_hh[r];
          r=2*256+ 64+lane; b5=b_ih[r]+b_hh[r]; }
#pragma unroll
        for (int g=0; g<4; ++g){
            const float* src = W_ih_rest + ((size_t)2*256 + g*64+lane)*64;
#pragma unroll
            for (int d=0; d<8; ++d) *(uint4*)&s_wih[2+g][d][lane][0] = pack8(src + 8*d);
        }
        { int r;
          r=3*256+  0+lane; b6=b_ih[r]+b_hh[r];
          r=3*256+ 64+lane; b7=b_ih[r]+b_hh[r];
          r=3*256+128+lane; b8=b_ih[r]+b_hh[r];
          r=3*256+192+lane; b9=b_ih[r]+b_hh[r]; }
    }
    __syncthreads();

// ---- recurrence step, no-lo, even/odd-d split chains (8 chains, 16-deep) ----
#define R_STEPN(L, WB, LASTF, T, C, CST) do{                                   \
    const int buf_ = (C)&1;                                                    \
    float xi_ = s_xg[buf_][L][T][      lane];                                  \
    float xf_ = s_xg[buf_][L][T][ 64 + lane];                                  \
    float xgg_= s_xg[buf_][L][T][128 + lane];                                  \
    float xo_ = s_xg[buf_][L][T][192 + lane];                                  \
    float ai0=0,ai1=0, af0=0,af1=0, ag0=0,ag1=0, ao0=0,ao1=0;                  \
    _Pragma("unroll")                                                          \
    for (int d_=0; d_<8; d_+=2){                                               \
        uint4 h0_ = *(const uint4*)&s_h16[L][4*d_];                            \
        uint4 h1_ = *(const uint4*)&s_h16[L][4*d_+4];                          \
        uint4 woA_ = *(const uint4*)&s_wo[L][d_  ][lane][0];                   \
        uint4 woB_ = *(const uint4*)&s_wo[L][d_+1][lane][0];                   \
        DOT4(ai0, wU[(WB)+d_],      h0_); DOT4(ai1, wU[(WB)+d_+1],    h1_);    \
        DOT4(af0, wU[(WB)+8+d_],    h0_); DOT4(af1, wU[(WB)+8+d_+1],  h1_);    \
        DOT4(ag0, wU[(WB)+16+d_],   h0_); DOT4(ag1, wU[(WB)+16+d_+1], h1_);    \
        DOT4(ao0, woA_,             h0_); DOT4(ao1, woB_,             h1_);    \
    }                                                                          \
    float I_=sigmoid_(xi_+(ai0+ai1)), F_=sigmoid_(xf_+(af0+af1));              \
    float G_=tanh_(xgg_+(ag0+ag1)),   O_=sigmoid_(xo_+(ao0+ao1));              \
    CST = fmaf(F_, CST, I_*G_);                                                \
    float h_ = O_*tanh_(CST);                                                  \
    __half hhi_=__float2half(h_);                                              \
    ((__half*)&s_h16[L][0])[lane]=hhi_;                                        \
    if (!(LASTF)){                                                             \
        ((__half*)&s_hh[(L)<4?(L):0][buf_][T][0])[lane]=hhi_;                  \
    } else if ((C)==NCH-1 && (T)==1){ hlast_g[lane]=h_; }                      \
}while(0)

// ---- G blocks, no-lo, d-outer / t-inner: weights read ONCE per supercycle ----
#define G4T(DMAX, WEXPR, H0, H1, XD0, XD1, B0_,B1_,B2_,B3_) do{                \
    float a00=(B0_),a01=(B1_),a02=(B2_),a03=(B3_);                             \
    float a10=(B0_),a11=(B1_),a12=(B2_),a13=(B3_);                             \
    _Pragma("unroll")                                                          \
    for (int d_=0; d_<(DMAX); ++d_){                                           \
        uint4 w0_=WEXPR(0,d_), w1_=WEXPR(1,d_), w2_=WEXPR(2,d_), w3_=WEXPR(3,d_);\
        uint4 h0_=*(const uint4*)&(H0)[4*d_];                                  \
        uint4 h1_=*(const uint4*)&(H1)[4*d_];                                  \
        DOT4(a00,w0_,h0_); DOT4(a01,w1_,h0_); DOT4(a02,w2_,h0_); DOT4(a03,w3_,h0_);\
        DOT4(a10,w0_,h1_); DOT4(a11,w1_,h1_); DOT4(a12,w2_,h1_); DOT4(a13,w3_,h1_);\
    }                                                                          \
    (XD0)[      lane]=a00; (XD0)[ 64+lane]=a01;                                \
    (XD0)[128+lane]=a02;   (XD0)[192+lane]=a03;                                \
    (XD1)[      lane]=a10; (XD1)[ 64+lane]=a11;                                \
    (XD1)[128+lane]=a12;   (XD1)[192+lane]=a13;                                \
}while(0)

#define G2T(DMAX, WEXPR, H0, H1, XD0, XD1, ROWOFF, B0_,B1_) do{                \
    float a00=(B0_),a01=(B1_), a10=(B0_),a11=(B1_);                            \
    _Pragma("unroll")                                                          \
    for (int d_=0; d_<(DMAX); ++d_){                                           \
        uint4 wa_ = WEXPR(0,d_), wb_ = WEXPR(1,d_);                            \
        uint4 h0_=*(const uint4*)&(H0)[4*d_];                                  \
        uint4 h1_=*(const uint4*)&(H1)[4*d_];                                  \
        DOT4(a00,wa_,h0_); DOT4(a01,wb_,h0_);                                  \
        DOT4(a10,wa_,h1_); DOT4(a11,wb_,h1_);                                  \
    }                                                                          \
    (XD0)[(ROWOFF)+lane]=a00; (XD0)[(ROWOFF)+64+lane]=a01;                     \
    (XD1)[(ROWOFF)+lane]=a10; (XD1)[(ROWOFF)+64+lane]=a11;                     \
}while(0)

// weight selectors
#define W_L1(g,d)  wU[(g)*8+(d)]
#define W_L2R(g,d) wU[32+(g)*8+(d)]
#define W_L0(g,d)  wU[24+(g)*6+(d)]
#define W_L2L(g,d) (*(const uint4*)&s_wih[(g)][d][lane][0])
#define W_L3(g,d)  (*(const uint4*)&s_wih[2+(g)][d][lane][0])
#define W_L4A(g,d) (*(const uint4*)&s_wih[6+(g)][d][lane][0])
#define W_L4B(g,d) (*(const uint4*)&s_wih[8+(g)][d][lane][0])

#define STAGE_X() do{                                                          \
    const int bufx = k & 1;                                                    \
    _Pragma("unroll")                                                          \
    for (int r=0; r<2; ++r){                                                   \
        const int i = lane + 64*r;                                             \
        if (i < 90){                                                           \
            float v = x_s[(size_t)k*90 + i];                                   \
            const int t = i/45, d = i - 45*t;                                  \
            ((__half*)&s_x[bufx][t][0])[d] = __float2half(v);                  \
        }                                                                      \
    }                                                                          \
}while(0)

// per-wave supercycle bodies (shared by fast/slow path; guards only in slow)
#define BODY_W0(GUARDED) do{                                                   \
    const int c0=k-2, c1=k-4, cl=k-9;                                          \
    if (!(GUARDED) || (c0>=0 && c0<NCH)){ R_STEPN(0,  0, 0, 0, c0, cA); }      \
    if (!(GUARDED) || (c1>=0 && c1<NCH)){ R_STEPN(1, 24, 0, 0, c1, cB); }      \
    if (!(GUARDED) || (c0>=0 && c0<NCH)){ R_STEPN(0,  0, 0, 1, c0, cA); }      \
    if (!(GUARDED) || (c1>=0 && c1<NCH)){ R_STEPN(1, 24, 0, 1, c1, cB); }      \
    if (!(GUARDED) || (cl>=0 && cl<NCH)){                                      \
        const int bl=cl&1;                                                     \
        G2T(8, W_L4A, (&s_hh[3][bl][0][0]), (&s_hh[3][bl][1][0]),              \
            (&s_xg[bl][4][0][0]), (&s_xg[bl][4][1][0]), 0, b0,b1); }           \
}while(0)

#define BODY_W1(GUARDED) do{                                                   \
    const int c2=k-6, c3=k-8, cl=k-9;                                          \
    if (!(GUARDED) || (c2>=0 && c2<NCH)){ R_STEPN(2,  0, 0, 0, c2, cA); }      \
    if (!(GUARDED) || (c3>=0 && c3<NCH)){ R_STEPN(3, 24, 0, 0, c3, cB); }      \
    if (!(GUARDED) || (c2>=0 && c2<NCH)){ R_STEPN(2,  0, 0, 1, c2, cA); }      \
    if (!(GUARDED) || (c3>=0 && c3<NCH)){ R_STEPN(3, 24, 0, 1, c3, cB); }      \
    if (!(GUARDED) || (cl>=0 && cl<NCH)){                                      \
        const int bl=cl&1;                                                     \
        G2T(8, W_L4B, (&s_hh[3][bl][0][0]), (&s_hh[3][bl][1][0]),              \
            (&s_xg[bl][4][0][0]), (&s_xg[bl][4][1][0]), 128, b0,b1); }         \
}while(0)

#define BODY_W2(GUARDED) do{                                                   \
    if (!(GUARDED) || (k < NCH)) STAGE_X();                                    \
    const int c4=k-10, cg0=k-1, cg2=k-5;                                       \
    if (!(GUARDED) || (c4>=0 && c4<NCH)){ R_STEPN(4, 0, 1, 0, c4, cA); }       \
    if (!(GUARDED) || (cg0>=0 && cg0<NCH)){                                    \
        const int bg=cg0&1;                                                    \
        G4T(6, W_L0, (&s_x[bg][0][0]), (&s_x[bg][1][0]),                       \
            (&s_xg[bg][0][0][0]), (&s_xg[bg][0][1][0]), b0,b1,b2,b3); }        \
    if (!(GUARDED) || (c4>=0 && c4<NCH)){ R_STEPN(4, 0, 1, 1, c4, cA); }       \
    if (!(GUARDED) || (cg2>=0 && cg2<NCH)){                                    \
        const int bg=cg2&1;                                                    \
        G2T(8, W_L2L, (&s_hh[1][bg][0][0]), (&s_hh[1][bg][1][0]),              \
            (&s_xg[bg][2][0][0]), (&s_xg[bg][2][1][0]), 128, b4,b5); }         \
}while(0)

#define BODY_W3(GUARDED) do{                                                   \
    const int cg1=k-3, cg2=k-5, cg3=k-7;                                       \
    if (!(GUARDED) || (cg1>=0 && cg1<NCH)){                                    \
        const int bg=cg1&1;                                                    \
        G4T(8, W_L1, (&s_hh[0][bg][0][0]), (&s_hh[0][bg][1][0]),               \
            (&s_xg[bg][1][0][0]), (&s_xg[bg][1][1][0]), b0,b1,b2,b3); }        \
    if (!(GUARDED) || (cg2>=0 && cg2<NCH)){                                    \
        const int bg=cg2&1;                                                    \
        G2T(8, W_L2R, (&s_hh[1][bg][0][0]), (&s_hh[1][bg][1][0]),              \
            (&s_xg[bg][2][0][0]), (&s_xg[bg][2][1][0]), 0, b4,b5); }           \
    if (!(GUARDED) || (cg3>=0 && cg3<NCH)){                                    \
        const int bg=cg3&1;                                                    \
        G4T(8, W_L3, (&s_hh[2][bg][0][0]), (&s_hh[2][bg][1][0]),               \
            (&s_xg[bg][3][0][0]), (&s_xg[bg][3][1][0]), b6,b7,b8,b9); }        \
}while(0)

    // ================= supercycle loop =================
    for (int k=0; k<KMAX; ++k){
        if (k >= 10 && k < NCH){
            // ---------- FAST PATH: all pieces valid, no guards ----------
            if      (wave == 0) BODY_W0(0);
            else if (wave == 1) BODY_W1(0);
            else if (wave == 2) BODY_W2(0);
            else                BODY_W3(0);
        } else {
            // ---------- SLOW PATH: prologue/epilogue, guarded ----------
            if      (wave == 0) BODY_W0(1);
            else if (wave == 1) BODY_W1(1);
            else if (wave == 2) BODY_W2(1);
            else                BODY_W3(1);
        }
        __syncthreads();
    }
}

// MLP head: features = gelu(last @ Wl^T + bl); out = relu(features @ Wo^T + bo)
// d_out layout: out[256*4] first, then features[256*128].
__global__ __launch_bounds__(128)
void head_kernel(const float* __restrict__ h_last,  // [256, 64]
                 const float* __restrict__ Wl,      // [128, 64]
                 const float* __restrict__ bl,      // [128]
                 const float* __restrict__ Wo,      // [4, 128]
                 const float* __restrict__ bo,      // [4]
                 float* __restrict__ d_out)
{
    __shared__ float s_last[HID];
    __shared__ float s_feat[128];
    const int s = blockIdx.x;
    const int j = threadIdx.x;

    if (j < HID) s_last[j] = h_last[(size_t)s * HID + j];
    __syncthreads();

    float acc = bl[j];
#pragma unroll
    for (int k = 0; k < HID; ++k)
        acc = fmaf(s_last[k], Wl[j * HID + k], acc);
    float f = 0.5f * acc * (1.0f + erff(acc * 0.70710678118654752440f));
    d_out[256 * 4 + s * 128 + j] = f;
    s_feat[j] = f;
    __syncthreads();

    if (j < 4) {
        float a = bo[j];
#pragma unroll
        for (int k = 0; k < 128; ++k)
            a = fmaf(s_feat[k], Wo[j * 128 + k], a);
        d_out[s * 4 + j] = fmaxf(a, 0.0f);
    }
}

extern "C" void kernel_launch(void* const* d_in, const int* in_sizes, int n_in,
                              void* d_out, int out_size, void* d_ws, size_t ws_size,
                              hipStream_t stream)
{
    const float* x         = (const float*)d_in[0];  // [256, 2048, 45]
    const float* W_ih0     = (const float*)d_in[1];  // [256, 45]
    const float* W_ih_rest = (const float*)d_in[2];  // [4, 256, 64]
    const float* W_hh      = (const float*)d_in[3];  // [5, 256, 64]
    const float* b_ih      = (const float*)d_in[4];  // [5, 256]
    const float* b_hh      = (const float*)d_in[5];  // [5, 256]
    const float* Wl        = (const float*)d_in[6];  // [128, 64]
    const float* bl        = (const float*)d_in[7];  // [128]
    const float* Wo        = (const float*)d_in[8];  // [4, 128]
    const float* bo        = (const float*)d_in[9];  // [4]

    float* h_last = (float*)d_ws;   // [256, 64] fp32

    lstm_pipe4<<<256, 256, 0, stream>>>(
        x, W_ih0, W_ih_rest, W_hh, b_ih, b_hh, h_last);
    head_kernel<<<256, 128, 0, stream>>>(h_last, Wl, bl, Wo, bo, (float*)d_out);
}